// Round 3
// baseline (709.001 us; speedup 1.0000x reference)
//
#include <hip/hip_runtime.h>
#include <hip/hip_bf16.h>
#include <stdint.h>

typedef unsigned int uint;
typedef unsigned short ushort;

#define DD 128

__device__ __forceinline__ float bf2f(ushort h){ return __uint_as_float(((uint)h)<<16); }
__device__ __forceinline__ ushort f2bf(float f){
    uint u = __float_as_uint(f);
    u += 0x7fffu + ((u>>16)&1u);
    return (ushort)(u>>16);
}

// flags[0]=edge_index is int64, flags[1]=x is bf16, flags[2]=W is bf16
__device__ __forceinline__ int is_bf16_probe(const ushort* p){
    int sane = 0;
    for (int i=0;i<64;i++){
        uint u = p[2*i];
        uint e = (u>>7)&0xffu;
        sane += (e>=90u && e<=160u) ? 1 : 0;
    }
    return sane >= 48;
}
__global__ void k_detect(const int* ei, const ushort* x, const ushort* W1, int* flags){
    if (threadIdx.x==0){
        int ok = 1;
        for (int i=0;i<32;i++) ok &= (ei[2*i+1]==0);
        flags[0] = ok;
        flags[1] = is_bf16_probe(x);
        flags[2] = is_bf16_probe(W1);
    }
}

// canonicalize W1,W2,Wfc (16384 each) + b1,b2,bfc (128 each) to f32
__global__ void k_canon(const void* s0,const void* s1,const void* s2,
                        const void* s3,const void* s4,const void* s5,
                        float* d0,float* d1,float* d2,float* d3,float* d4,float* d5,
                        const int* flags){
    int f = flags[2];
    int i = blockIdx.x*blockDim.x + threadIdx.x;
    const void* s; float* d; int off;
    if (i < 49152){
        int r = i>>14; off = i & 16383;
        s = (r==0)?s0:((r==1)?s1:s2);
        d = (r==0)?d0:((r==1)?d1:d2);
    } else {
        int j = i - 49152; int r = j>>7; off = j & 127;
        if (r >= 3) return;
        s = (r==0)?s3:((r==1)?s4:s5);
        d = (r==0)?d3:((r==1)?d4:d5);
    }
    d[off] = f ? bf2f(((const ushort*)s)[off]) : ((const float*)s)[off];
}

__global__ void k_init(int* counts, float* pooled, int M, int PM){
    int i = blockIdx.x*blockDim.x + threadIdx.x;
    int stride = gridDim.x*blockDim.x;
    for (int j=i; j<M; j+=stride) counts[j]=0;
    for (int j=i; j<PM; j+=stride) pooled[j]=0.f;
}

__global__ void k_count(const int* ei, const int* flags, int* counts, int E){
    int f = flags[0];
    int i = blockIdx.x*blockDim.x + threadIdx.x;
    int stride = gridDim.x*blockDim.x;
    for (int e=i; e<E; e+=stride){
        int d = f ? ei[2*(E+e)] : ei[E+e];
        atomicAdd(&counts[d], 1);
    }
}

__global__ void k_scan_a(const int* counts, int* bsum, int M){
    __shared__ int ts[256];
    int b = blockIdx.x, t = threadIdx.x;
    int base = b*1024 + t*4;
    int s = 0;
    #pragma unroll
    for (int j=0;j<4;j++){ int i = base+j; if (i<M) s += counts[i]; }
    ts[t] = s; __syncthreads();
    for (int off=128; off>0; off>>=1){ if (t<off) ts[t] += ts[t+off]; __syncthreads(); }
    if (t==0) bsum[b] = ts[0];
}

__global__ void k_scan_b(const int* bsum, int* boff, int* rowptr, int NB, int M){
    __shared__ int ts[256];
    int t = threadIdx.x;
    int v = (t<NB) ? bsum[t] : 0;
    ts[t] = v; __syncthreads();
    for (int off=1; off<256; off<<=1){
        int x = (t>=off) ? ts[t-off] : 0;
        __syncthreads();
        ts[t] += x;
        __syncthreads();
    }
    if (t<NB) boff[t] = ts[t] - v;
    if (t==255) rowptr[M] = ts[255];
}

__global__ void k_scan_c(const int* counts, const int* boff, int* rowptr, int* cursor, int M){
    __shared__ int ts[256];
    int b = blockIdx.x, t = threadIdx.x;
    int base = b*1024 + t*4;
    int v[4]; int s = 0;
    #pragma unroll
    for (int j=0;j<4;j++){ int i = base+j; v[j] = (i<M) ? counts[i] : 0; s += v[j]; }
    ts[t] = s; __syncthreads();
    for (int off=1; off<256; off<<=1){
        int x = (t>=off) ? ts[t-off] : 0;
        __syncthreads();
        ts[t] += x;
        __syncthreads();
    }
    int o = boff[b] + (ts[t] - s);
    #pragma unroll
    for (int j=0;j<4;j++){
        int i = base+j;
        if (i<M){ rowptr[i] = o; cursor[i] = o; o += v[j]; }
    }
}

__global__ void k_fill(const int* ei, const int* flags, int* cursor, int* srcb, int E){
    int f = flags[0];
    int i = blockIdx.x*blockDim.x + threadIdx.x;
    int stride = gridDim.x*blockDim.x;
    for (int e=i; e<E; e+=stride){
        int d = f ? ei[2*(E+e)] : ei[E+e];
        int s = f ? ei[2*e]     : ei[e];
        int pos = atomicAdd(&cursor[d], 1);
        srcb[pos] = s;
    }
}

__global__ void k_dinv(const int* counts, float* dinv, int M){
    int i = blockIdx.x*blockDim.x + threadIdx.x;
    if (i<M) dinv[i] = rsqrtf((float)(counts[i]+1));
}

// Hp[n,c] = bf16( dinv[n] * sum_k X[n,k]*Wc[k,c] ); X dtype from flags[1] (or forced bf16)
__global__ __launch_bounds__(256) void k_gemm(const ushort* Xb, const float* Xf,
                                              const float* __restrict__ Wc,
                                              const float* __restrict__ dinv,
                                              const int* __restrict__ flags, int force_bf16,
                                              ushort* __restrict__ Hp, int M){
    __shared__ float Wl[64*128];   // 32 KB
    __shared__ float Xl[32*69];    // 8.8 KB, pad 69 -> conflict-free row reads
    int t = threadIdx.x;
    int n0 = blockIdx.x*32;
    int xbf = force_bf16 ? 1 : flags[1];

    int c4 = (t & 31) * 4;
    int r4 = (t >> 5) * 4;
    float acc[4][4];
    #pragma unroll
    for (int i=0;i<4;i++)
        #pragma unroll
        for (int j=0;j<4;j++) acc[i][j] = 0.f;

    for (int h=0; h<2; ++h){
        // stage W half (rows h*64..h*64+63, f32): 8192 floats = 2048 float4
        {
            const float4* Ws = (const float4*)(Wc + h*64*DD);
            float4* Wd = (float4*)Wl;
            #pragma unroll
            for (int j=0;j<8;j++) Wd[t + j*256] = Ws[t + j*256];
        }
        // stage X: row t&31, 8-elem k-chunk (t>>5)*8 within this 64-k half
        {
            int r  = t & 31;
            int k0 = (t >> 5) * 8;
            int n = n0 + r;
            float v[8];
            if (n < M){
                if (xbf){
                    const ushort* p = Xb + (size_t)n*DD + h*64 + k0;
                    uint4 a = *(const uint4*)p;
                    uint av[4] = {a.x,a.y,a.z,a.w};
                    #pragma unroll
                    for (int j=0;j<4;j++){
                        v[2*j]   = __uint_as_float(av[j]<<16);
                        v[2*j+1] = __uint_as_float(av[j]&0xffff0000u);
                    }
                } else {
                    const float* p = Xf + (size_t)n*DD + h*64 + k0;
                    float4 a = *(const float4*)p;
                    float4 b = *(const float4*)(p+4);
                    v[0]=a.x; v[1]=a.y; v[2]=a.z; v[3]=a.w;
                    v[4]=b.x; v[5]=b.y; v[6]=b.z; v[7]=b.w;
                }
            } else {
                #pragma unroll
                for (int j=0;j<8;j++) v[j]=0.f;
            }
            float* xd = &Xl[r*69 + k0];
            #pragma unroll
            for (int j=0;j<8;j++) xd[j] = v[j];
        }
        __syncthreads();

        #pragma unroll 4
        for (int k=0;k<64;k++){
            float4 wv = *(const float4*)&Wl[k*DD + c4];
            float a0 = Xl[(r4+0)*69 + k];
            float a1 = Xl[(r4+1)*69 + k];
            float a2 = Xl[(r4+2)*69 + k];
            float a3 = Xl[(r4+3)*69 + k];
            acc[0][0]=fmaf(a0,wv.x,acc[0][0]); acc[0][1]=fmaf(a0,wv.y,acc[0][1]);
            acc[0][2]=fmaf(a0,wv.z,acc[0][2]); acc[0][3]=fmaf(a0,wv.w,acc[0][3]);
            acc[1][0]=fmaf(a1,wv.x,acc[1][0]); acc[1][1]=fmaf(a1,wv.y,acc[1][1]);
            acc[1][2]=fmaf(a1,wv.z,acc[1][2]); acc[1][3]=fmaf(a1,wv.w,acc[1][3]);
            acc[2][0]=fmaf(a2,wv.x,acc[2][0]); acc[2][1]=fmaf(a2,wv.y,acc[2][1]);
            acc[2][2]=fmaf(a2,wv.z,acc[2][2]); acc[2][3]=fmaf(a2,wv.w,acc[2][3]);
            acc[3][0]=fmaf(a3,wv.x,acc[3][0]); acc[3][1]=fmaf(a3,wv.y,acc[3][1]);
            acc[3][2]=fmaf(a3,wv.z,acc[3][2]); acc[3][3]=fmaf(a3,wv.w,acc[3][3]);
        }
        __syncthreads();
    }

    #pragma unroll
    for (int i=0;i<4;i++){
        int n = n0 + r4 + i;
        if (n < M){
            float w = dinv[n];
            uint2 o;
            o.x = (uint)f2bf(acc[i][0]*w) | ((uint)f2bf(acc[i][1]*w)<<16);
            o.y = (uint)f2bf(acc[i][2]*w) | ((uint)f2bf(acc[i][3]*w)<<16);
            *(uint2*)&Hp[(size_t)n*DD + c4] = o;
        }
    }
}

// one wave per node: out[n] = relu( dinv[n]*(Hp[n] + sum_{e} Hp[src]) + bias )
__global__ __launch_bounds__(256) void k_gather(const ushort* __restrict__ Hp,
                                                const int* __restrict__ rowptr,
                                                const int* __restrict__ srcb,
                                                const float* __restrict__ dinv,
                                                const float* __restrict__ bc,
                                                ushort* __restrict__ Xout, int M){
    int wid  = (int)((blockIdx.x*(size_t)blockDim.x + threadIdx.x) >> 6);
    int lane = threadIdx.x & 63;
    if (wid >= M) return;
    const uint* Hp32 = (const uint*)Hp;

    uint v = Hp32[(size_t)wid*64 + lane];            // self-loop
    float a0 = __uint_as_float(v<<16);
    float a1 = __uint_as_float(v & 0xffff0000u);

    int rp  = rowptr[wid];
    int rp1 = rowptr[wid+1];
    while (rp < rp1){
        int m = rp1 - rp; if (m > 64) m = 64;
        int idx = (lane < m) ? srcb[rp + lane] : 0;
        int j = 0;
        for (; j+4 <= m; j += 4){
            int s0 = __shfl(idx, j,   64);
            int s1 = __shfl(idx, j+1, 64);
            int s2 = __shfl(idx, j+2, 64);
            int s3 = __shfl(idx, j+3, 64);
            uint u0 = Hp32[(size_t)s0*64 + lane];
            uint u1 = Hp32[(size_t)s1*64 + lane];
            uint u2 = Hp32[(size_t)s2*64 + lane];
            uint u3 = Hp32[(size_t)s3*64 + lane];
            a0 += __uint_as_float(u0<<16); a1 += __uint_as_float(u0&0xffff0000u);
            a0 += __uint_as_float(u1<<16); a1 += __uint_as_float(u1&0xffff0000u);
            a0 += __uint_as_float(u2<<16); a1 += __uint_as_float(u2&0xffff0000u);
            a0 += __uint_as_float(u3<<16); a1 += __uint_as_float(u3&0xffff0000u);
        }
        for (; j<m; j++){
            int s = __shfl(idx, j, 64);
            uint u = Hp32[(size_t)s*64 + lane];
            a0 += __uint_as_float(u<<16); a1 += __uint_as_float(u&0xffff0000u);
        }
        rp += m;
    }

    float w = dinv[wid];
    float o0 = fmaxf(fmaf(a0, w, bc[2*lane]),   0.f);
    float o1 = fmaxf(fmaf(a1, w, bc[2*lane+1]), 0.f);
    ((uint*)Xout)[(size_t)wid*64 + lane] = (uint)f2bf(o0) | ((uint)f2bf(o1)<<16);
}

__global__ void k_pool(const ushort* __restrict__ X3, const int* __restrict__ batch,
                       const int* __restrict__ flags, float* __restrict__ pooled, int M){
    int f = flags[0];
    int c = threadIdx.x;          // 0..127
    int n0 = blockIdx.x * 512;
    if (n0 >= M) return;
    int nend = n0 + 512; if (nend > M) nend = M;
    float acc = 0.f;
    int cur = f ? batch[2*n0] : batch[n0];
    for (int n=n0; n<nend; n++){
        int g = f ? batch[2*n] : batch[n];
        if (g != cur){
            atomicAdd(&pooled[cur*DD + c], acc);
            acc = 0.f; cur = g;
        }
        acc += bf2f(X3[(size_t)n*DD + c]);
    }
    atomicAdd(&pooled[cur*DD + c], acc);
}

__global__ void k_cnt(const int* __restrict__ batch, const int* __restrict__ flags,
                      float* __restrict__ cntf, int M, int G){
    int f = flags[0];
    int g = blockIdx.x*blockDim.x + threadIdx.x;
    if (g >= G) return;
    int lo = 0, hi = M;
    while (lo < hi){ int mid = (lo+hi)>>1; int bv = f ? batch[2*mid] : batch[mid]; if (bv > g) hi = mid; else lo = mid+1; }
    int ub_g = lo;
    lo = 0; hi = M;
    while (lo < hi){ int mid = (lo+hi)>>1; int bv = f ? batch[2*mid] : batch[mid]; if (bv > g-1) hi = mid; else lo = mid+1; }
    cntf[g] = (float)(ub_g - lo);
}

__global__ void k_fc(const float* __restrict__ pooled, const float* __restrict__ cntf,
                     const float* __restrict__ Wcf, const float* __restrict__ bcf,
                     const int* __restrict__ flags, ushort* out16, float* out32){
    __shared__ float p[128];
    int g = blockIdx.x, c = threadIdx.x;
    p[c] = pooled[g*DD + c] / fmaxf(cntf[g], 1.f);
    __syncthreads();
    float acc = bcf[c];
    #pragma unroll 8
    for (int k=0;k<128;k++) acc = fmaf(p[k], Wcf[k*DD + c], acc);
    float r = fmaxf(acc, 0.f);
    if (flags[1]) out16[g*DD + c] = f2bf(r);
    else          out32[g*DD + c] = r;
}

extern "C" void kernel_launch(void* const* d_in, const int* in_sizes, int n_in,
                              void* d_out, int out_size, void* d_ws, size_t ws_size,
                              hipStream_t stream) {
    const void* x    = d_in[0];
    const int*  ei   = (const int*)d_in[1];
    const int*  bat  = (const int*)d_in[2];
    const void* W1   = d_in[3];
    const void* b1   = d_in[4];
    const void* W2   = d_in[5];
    const void* b2   = d_in[6];
    const void* Wfc  = d_in[7];
    const void* bfc  = d_in[8];

    int M = in_sizes[0] / DD;       // 100000 nodes
    int E = in_sizes[1] / 2;        // 1600000 edges
    int G = out_size / DD;          // 64 graphs

    char* w = (char*)d_ws;
    auto alloc = [&](size_t bytes)->void*{ void* p = (void*)w; w += (bytes + 255) & ~(size_t)255; return p; };
    int*    flags  = (int*)   alloc(16);
    int*    counts = (int*)   alloc((size_t)M*4);
    int*    rowptr = (int*)   alloc((size_t)(M+1)*4);
    int*    cursor = (int*)   alloc((size_t)M*4);
    int*    bsum   = (int*)   alloc(256*4);
    int*    boff   = (int*)   alloc(256*4);
    float*  dinv   = (float*) alloc((size_t)M*4);
    float*  cntf   = (float*) alloc((size_t)G*4);
    float*  pooled = (float*) alloc((size_t)G*DD*4);
    float*  Wc1    = (float*) alloc(16384*4);
    float*  Wc2    = (float*) alloc(16384*4);
    float*  Wcf    = (float*) alloc(16384*4);
    float*  bc1    = (float*) alloc(128*4);
    float*  bc2    = (float*) alloc(128*4);
    float*  bcf    = (float*) alloc(128*4);
    int*    srcb   = (int*)   alloc((size_t)E*4);
    ushort* Hp     = (ushort*)alloc((size_t)M*DD*2);
    ushort* X2     = (ushort*)alloc((size_t)M*DD*2);
    (void)ws_size; (void)n_in;

    int NB = (M + 1023) / 1024;

    k_detect<<<1, 64, 0, stream>>>(ei, (const ushort*)x, (const ushort*)W1, flags);
    k_canon <<<194, 256, 0, stream>>>(W1, W2, Wfc, b1, b2, bfc,
                                      Wc1, Wc2, Wcf, bc1, bc2, bcf, flags);
    k_init  <<<512, 256, 0, stream>>>(counts, pooled, M, G*DD);
    k_count <<<2048, 256, 0, stream>>>(ei, flags, counts, E);
    k_scan_a<<<NB, 256, 0, stream>>>(counts, bsum, M);
    k_scan_b<<<1, 256, 0, stream>>>(bsum, boff, rowptr, NB, M);
    k_scan_c<<<NB, 256, 0, stream>>>(counts, boff, rowptr, cursor, M);
    k_fill  <<<2048, 256, 0, stream>>>(ei, flags, cursor, srcb, E);
    k_dinv  <<<(M+255)/256, 256, 0, stream>>>(counts, dinv, M);

    // layer 1 (X dtype per flags[1])
    k_gemm  <<<(M+31)/32, 256, 0, stream>>>((const ushort*)x, (const float*)x,
                                            Wc1, dinv, flags, 0, Hp, M);
    k_gather<<<(M+3)/4, 256, 0, stream>>>(Hp, rowptr, srcb, dinv, bc1, X2, M);
    // layer 2 (X2 is always bf16)
    k_gemm  <<<(M+31)/32, 256, 0, stream>>>(X2, (const float*)X2,
                                            Wc2, dinv, flags, 1, Hp, M);
    k_gather<<<(M+3)/4, 256, 0, stream>>>(Hp, rowptr, srcb, dinv, bc2, X2, M);

    // pool + fc
    k_pool<<<(M+511)/512, 128, 0, stream>>>(X2, bat, flags, pooled, M);
    k_cnt <<<(G+63)/64, 64, 0, stream>>>(bat, flags, cntf, M, G);
    k_fc  <<<G, 128, 0, stream>>>(pooled, cntf, Wcf, bcf, flags, (ushort*)d_out, (float*)d_out);
}

// Round 4
// 579.753 us; speedup vs baseline: 1.2229x; 1.2229x over previous
//
#include <hip/hip_runtime.h>
#include <hip/hip_bf16.h>
#include <stdint.h>

typedef unsigned int uint;
typedef unsigned short ushort;

#define DD 128

__device__ __forceinline__ float bf2f(ushort h){ return __uint_as_float(((uint)h)<<16); }
__device__ __forceinline__ ushort f2bf(float f){
    uint u = __float_as_uint(f);
    u += 0x7fffu + ((u>>16)&1u);
    return (ushort)(u>>16);
}

// flags[0]=edge_index is int64, flags[1]=x is bf16, flags[2]=W is bf16
__device__ __forceinline__ int is_bf16_probe(const ushort* p){
    int sane = 0;
    for (int i=0;i<64;i++){
        uint u = p[2*i];
        uint e = (u>>7)&0xffu;
        sane += (e>=90u && e<=160u) ? 1 : 0;
    }
    return sane >= 48;
}
__global__ void k_detect(const int* ei, const ushort* x, const ushort* W1, int* flags){
    if (threadIdx.x==0){
        int ok = 1;
        for (int i=0;i<32;i++) ok &= (ei[2*i+1]==0);
        flags[0] = ok;
        flags[1] = is_bf16_probe(x);
        flags[2] = is_bf16_probe(W1);
    }
}

// canonicalize W1,W2,Wfc (16384 each) + b1,b2,bfc (128 each) to f32
__global__ void k_canon(const void* s0,const void* s1,const void* s2,
                        const void* s3,const void* s4,const void* s5,
                        float* d0,float* d1,float* d2,float* d3,float* d4,float* d5,
                        const int* flags){
    int f = flags[2];
    int i = blockIdx.x*blockDim.x + threadIdx.x;
    const void* s; float* d; int off;
    if (i < 49152){
        int r = i>>14; off = i & 16383;
        s = (r==0)?s0:((r==1)?s1:s2);
        d = (r==0)?d0:((r==1)?d1:d2);
    } else {
        int j = i - 49152; int r = j>>7; off = j & 127;
        if (r >= 3) return;
        s = (r==0)?s3:((r==1)?s4:s5);
        d = (r==0)?d3:((r==1)?d4:d5);
    }
    d[off] = f ? bf2f(((const ushort*)s)[off]) : ((const float*)s)[off];
}

__global__ void k_init(int* counts, float* pooled, int M, int PM){
    int i = blockIdx.x*blockDim.x + threadIdx.x;
    int stride = gridDim.x*blockDim.x;
    for (int j=i; j<M; j+=stride) counts[j]=0;
    for (int j=i; j<PM; j+=stride) pooled[j]=0.f;
}

__global__ void k_count(const int* ei, const int* flags, int* counts, int E){
    int f = flags[0];
    int i = blockIdx.x*blockDim.x + threadIdx.x;
    int stride = gridDim.x*blockDim.x;
    for (int e=i; e<E; e+=stride){
        int d = f ? ei[2*(E+e)] : ei[E+e];
        atomicAdd(&counts[d], 1);
    }
}

__global__ void k_scan_a(const int* counts, int* bsum, int M){
    __shared__ int ts[256];
    int b = blockIdx.x, t = threadIdx.x;
    int base = b*1024 + t*4;
    int s = 0;
    #pragma unroll
    for (int j=0;j<4;j++){ int i = base+j; if (i<M) s += counts[i]; }
    ts[t] = s; __syncthreads();
    for (int off=128; off>0; off>>=1){ if (t<off) ts[t] += ts[t+off]; __syncthreads(); }
    if (t==0) bsum[b] = ts[0];
}

__global__ void k_scan_b(const int* bsum, int* boff, int* rowptr, int NB, int M){
    __shared__ int ts[256];
    int t = threadIdx.x;
    int v = (t<NB) ? bsum[t] : 0;
    ts[t] = v; __syncthreads();
    for (int off=1; off<256; off<<=1){
        int x = (t>=off) ? ts[t-off] : 0;
        __syncthreads();
        ts[t] += x;
        __syncthreads();
    }
    if (t<NB) boff[t] = ts[t] - v;
    if (t==255) rowptr[M] = ts[255];
}

__global__ void k_scan_c(const int* counts, const int* boff, int* rowptr, int* cursor, int M){
    __shared__ int ts[256];
    int b = blockIdx.x, t = threadIdx.x;
    int base = b*1024 + t*4;
    int v[4]; int s = 0;
    #pragma unroll
    for (int j=0;j<4;j++){ int i = base+j; v[j] = (i<M) ? counts[i] : 0; s += v[j]; }
    ts[t] = s; __syncthreads();
    for (int off=1; off<256; off<<=1){
        int x = (t>=off) ? ts[t-off] : 0;
        __syncthreads();
        ts[t] += x;
        __syncthreads();
    }
    int o = boff[b] + (ts[t] - s);
    #pragma unroll
    for (int j=0;j<4;j++){
        int i = base+j;
        if (i<M){ rowptr[i] = o; cursor[i] = o; o += v[j]; }
    }
}

__global__ void k_fill(const int* ei, const int* flags, int* cursor, int* srcb, int E){
    int f = flags[0];
    int i = blockIdx.x*blockDim.x + threadIdx.x;
    int stride = gridDim.x*blockDim.x;
    for (int e=i; e<E; e+=stride){
        int d = f ? ei[2*(E+e)] : ei[E+e];
        int s = f ? ei[2*e]     : ei[e];
        int pos = atomicAdd(&cursor[d], 1);
        srcb[pos] = s;
    }
}

__global__ void k_dinv(const int* counts, float* dinv, int M){
    int i = blockIdx.x*blockDim.x + threadIdx.x;
    if (i<M) dinv[i] = rsqrtf((float)(counts[i]+1));
}

// Hp[n,c] = bf16( dinv[n] * sum_k X[n,k]*Wc[k,c] ); X dtype from flags[1] (or forced bf16)
__global__ __launch_bounds__(256) void k_gemm(const ushort* Xb, const float* Xf,
                                              const float* __restrict__ Wc,
                                              const float* __restrict__ dinv,
                                              const int* __restrict__ flags, int force_bf16,
                                              ushort* __restrict__ Hp, int M){
    __shared__ float Wl[64*128];   // 32 KB
    __shared__ float Xl[32*69];    // 8.8 KB, pad 69 -> conflict-free row reads
    int t = threadIdx.x;
    int n0 = blockIdx.x*32;
    int xbf = force_bf16 ? 1 : flags[1];

    int c4 = (t & 31) * 4;
    int r4 = (t >> 5) * 4;
    float acc[4][4];
    #pragma unroll
    for (int i=0;i<4;i++)
        #pragma unroll
        for (int j=0;j<4;j++) acc[i][j] = 0.f;

    for (int h=0; h<2; ++h){
        // stage W half (rows h*64..h*64+63, f32): 8192 floats = 2048 float4
        {
            const float4* Ws = (const float4*)(Wc + h*64*DD);
            float4* Wd = (float4*)Wl;
            #pragma unroll
            for (int j=0;j<8;j++) Wd[t + j*256] = Ws[t + j*256];
        }
        // stage X: row t&31, 8-elem k-chunk (t>>5)*8 within this 64-k half
        {
            int r  = t & 31;
            int k0 = (t >> 5) * 8;
            int n = n0 + r;
            float v[8];
            if (n < M){
                if (xbf){
                    const ushort* p = Xb + (size_t)n*DD + h*64 + k0;
                    uint4 a = *(const uint4*)p;
                    uint av[4] = {a.x,a.y,a.z,a.w};
                    #pragma unroll
                    for (int j=0;j<4;j++){
                        v[2*j]   = __uint_as_float(av[j]<<16);
                        v[2*j+1] = __uint_as_float(av[j]&0xffff0000u);
                    }
                } else {
                    const float* p = Xf + (size_t)n*DD + h*64 + k0;
                    float4 a = *(const float4*)p;
                    float4 b = *(const float4*)(p+4);
                    v[0]=a.x; v[1]=a.y; v[2]=a.z; v[3]=a.w;
                    v[4]=b.x; v[5]=b.y; v[6]=b.z; v[7]=b.w;
                }
            } else {
                #pragma unroll
                for (int j=0;j<8;j++) v[j]=0.f;
            }
            float* xd = &Xl[r*69 + k0];
            #pragma unroll
            for (int j=0;j<8;j++) xd[j] = v[j];
        }
        __syncthreads();

        #pragma unroll 4
        for (int k=0;k<64;k++){
            float4 wv = *(const float4*)&Wl[k*DD + c4];
            float a0 = Xl[(r4+0)*69 + k];
            float a1 = Xl[(r4+1)*69 + k];
            float a2 = Xl[(r4+2)*69 + k];
            float a3 = Xl[(r4+3)*69 + k];
            acc[0][0]=fmaf(a0,wv.x,acc[0][0]); acc[0][1]=fmaf(a0,wv.y,acc[0][1]);
            acc[0][2]=fmaf(a0,wv.z,acc[0][2]); acc[0][3]=fmaf(a0,wv.w,acc[0][3]);
            acc[1][0]=fmaf(a1,wv.x,acc[1][0]); acc[1][1]=fmaf(a1,wv.y,acc[1][1]);
            acc[1][2]=fmaf(a1,wv.z,acc[1][2]); acc[1][3]=fmaf(a1,wv.w,acc[1][3]);
            acc[2][0]=fmaf(a2,wv.x,acc[2][0]); acc[2][1]=fmaf(a2,wv.y,acc[2][1]);
            acc[2][2]=fmaf(a2,wv.z,acc[2][2]); acc[2][3]=fmaf(a2,wv.w,acc[2][3]);
            acc[3][0]=fmaf(a3,wv.x,acc[3][0]); acc[3][1]=fmaf(a3,wv.y,acc[3][1]);
            acc[3][2]=fmaf(a3,wv.z,acc[3][2]); acc[3][3]=fmaf(a3,wv.w,acc[3][3]);
        }
        __syncthreads();
    }

    #pragma unroll
    for (int i=0;i<4;i++){
        int n = n0 + r4 + i;
        if (n < M){
            float w = dinv[n];
            uint2 o;
            o.x = (uint)f2bf(acc[i][0]*w) | ((uint)f2bf(acc[i][1]*w)<<16);
            o.y = (uint)f2bf(acc[i][2]*w) | ((uint)f2bf(acc[i][3]*w)<<16);
            *(uint2*)&Hp[(size_t)n*DD + c4] = o;
        }
    }
}

// one wave per node: out[n] = relu( dinv[n]*(Hp[n] + sum_{e} Hp[src]) + bias )
__global__ __launch_bounds__(256) void k_gather(const ushort* __restrict__ Hp,
                                                const int* __restrict__ rowptr,
                                                const int* __restrict__ srcb,
                                                const float* __restrict__ dinv,
                                                const float* __restrict__ bc,
                                                ushort* __restrict__ Xout, int M){
    int wid  = (int)((blockIdx.x*(size_t)blockDim.x + threadIdx.x) >> 6);
    int lane = threadIdx.x & 63;
    if (wid >= M) return;
    const uint* Hp32 = (const uint*)Hp;

    uint v = Hp32[(size_t)wid*64 + lane];            // self-loop
    float a0 = __uint_as_float(v<<16);
    float a1 = __uint_as_float(v & 0xffff0000u);

    int rp  = rowptr[wid];
    int rp1 = rowptr[wid+1];
    while (rp < rp1){
        int m = rp1 - rp; if (m > 64) m = 64;
        int idx = (lane < m) ? srcb[rp + lane] : 0;
        int j = 0;
        for (; j+4 <= m; j += 4){
            int s0 = __shfl(idx, j,   64);
            int s1 = __shfl(idx, j+1, 64);
            int s2 = __shfl(idx, j+2, 64);
            int s3 = __shfl(idx, j+3, 64);
            uint u0 = Hp32[(size_t)s0*64 + lane];
            uint u1 = Hp32[(size_t)s1*64 + lane];
            uint u2 = Hp32[(size_t)s2*64 + lane];
            uint u3 = Hp32[(size_t)s3*64 + lane];
            a0 += __uint_as_float(u0<<16); a1 += __uint_as_float(u0&0xffff0000u);
            a0 += __uint_as_float(u1<<16); a1 += __uint_as_float(u1&0xffff0000u);
            a0 += __uint_as_float(u2<<16); a1 += __uint_as_float(u2&0xffff0000u);
            a0 += __uint_as_float(u3<<16); a1 += __uint_as_float(u3&0xffff0000u);
        }
        for (; j<m; j++){
            int s = __shfl(idx, j, 64);
            uint u = Hp32[(size_t)s*64 + lane];
            a0 += __uint_as_float(u<<16); a1 += __uint_as_float(u&0xffff0000u);
        }
        rp += m;
    }

    float w = dinv[wid];
    float o0 = fmaxf(fmaf(a0, w, bc[2*lane]),   0.f);
    float o1 = fmaxf(fmaf(a1, w, bc[2*lane+1]), 0.f);
    ((uint*)Xout)[(size_t)wid*64 + lane] = (uint)f2bf(o0) | ((uint)f2bf(o1)<<16);
}

// mean-pool numerator, latency-optimized:
// 391 blocks x 256 thr; thread = (uint-channel c32=t&63, row=t>>6); row strides 4
// through a 256-node chunk. Loads grouped ahead of the branchy accumulate so
// 4 data + 4 batch loads are in flight per stall. batch[] loads are wave-uniform
// (row is constant per wave). ~200K f32 atomics onto 64*128 addrs.
__global__ __launch_bounds__(256) void k_pool(const ushort* __restrict__ X3,
                                              const int* __restrict__ batch,
                                              const int* __restrict__ flags,
                                              float* __restrict__ pooled, int M){
    int f = flags[0];
    int t = threadIdx.x;
    int c32 = t & 63;       // uint index -> channels 2*c32, 2*c32+1
    int row = t >> 6;       // 0..3, constant per wave
    int n0 = blockIdx.x * 256;
    if (n0 >= M) return;
    int nend = n0 + 256; if (nend > M) nend = M;
    const uint* X3u = (const uint*)X3;

    float a0 = 0.f, a1 = 0.f;
    int cur = -1;

    int n = n0 + row;
    #define POOL_PROC(gg, uu) \
        if ((gg) != cur){ \
            if (cur >= 0){ \
                atomicAdd(&pooled[cur*DD + 2*c32],   a0); \
                atomicAdd(&pooled[cur*DD + 2*c32+1], a1); \
            } \
            a0 = 0.f; a1 = 0.f; cur = (gg); \
        } \
        a0 += __uint_as_float((uu)<<16); \
        a1 += __uint_as_float((uu) & 0xffff0000u);

    for (; n + 12 < nend; n += 16){
        int g0 = f ? batch[2*n]      : batch[n];
        int g1 = f ? batch[2*(n+4)]  : batch[n+4];
        int g2 = f ? batch[2*(n+8)]  : batch[n+8];
        int g3 = f ? batch[2*(n+12)] : batch[n+12];
        uint u0 = X3u[(size_t)n*64      + c32];
        uint u1 = X3u[(size_t)(n+4)*64  + c32];
        uint u2 = X3u[(size_t)(n+8)*64  + c32];
        uint u3 = X3u[(size_t)(n+12)*64 + c32];
        POOL_PROC(g0, u0);
        POOL_PROC(g1, u1);
        POOL_PROC(g2, u2);
        POOL_PROC(g3, u3);
    }
    for (; n < nend; n += 4){
        int g = f ? batch[2*n] : batch[n];
        uint u = X3u[(size_t)n*64 + c32];
        POOL_PROC(g, u);
    }
    #undef POOL_PROC

    if (cur >= 0){
        atomicAdd(&pooled[cur*DD + 2*c32],   a0);
        atomicAdd(&pooled[cur*DD + 2*c32+1], a1);
    }
}

__global__ void k_cnt(const int* __restrict__ batch, const int* __restrict__ flags,
                      float* __restrict__ cntf, int M, int G){
    int f = flags[0];
    int g = blockIdx.x*blockDim.x + threadIdx.x;
    if (g >= G) return;
    int lo = 0, hi = M;
    while (lo < hi){ int mid = (lo+hi)>>1; int bv = f ? batch[2*mid] : batch[mid]; if (bv > g) hi = mid; else lo = mid+1; }
    int ub_g = lo;
    lo = 0; hi = M;
    while (lo < hi){ int mid = (lo+hi)>>1; int bv = f ? batch[2*mid] : batch[mid]; if (bv > g-1) hi = mid; else lo = mid+1; }
    cntf[g] = (float)(ub_g - lo);
}

__global__ void k_fc(const float* __restrict__ pooled, const float* __restrict__ cntf,
                     const float* __restrict__ Wcf, const float* __restrict__ bcf,
                     const int* __restrict__ flags, ushort* out16, float* out32){
    __shared__ float p[128];
    int g = blockIdx.x, c = threadIdx.x;
    p[c] = pooled[g*DD + c] / fmaxf(cntf[g], 1.f);
    __syncthreads();
    float acc = bcf[c];
    #pragma unroll 8
    for (int k=0;k<128;k++) acc = fmaf(p[k], Wcf[k*DD + c], acc);
    float r = fmaxf(acc, 0.f);
    if (flags[1]) out16[g*DD + c] = f2bf(r);
    else          out32[g*DD + c] = r;
}

extern "C" void kernel_launch(void* const* d_in, const int* in_sizes, int n_in,
                              void* d_out, int out_size, void* d_ws, size_t ws_size,
                              hipStream_t stream) {
    const void* x    = d_in[0];
    const int*  ei   = (const int*)d_in[1];
    const int*  bat  = (const int*)d_in[2];
    const void* W1   = d_in[3];
    const void* b1   = d_in[4];
    const void* W2   = d_in[5];
    const void* b2   = d_in[6];
    const void* Wfc  = d_in[7];
    const void* bfc  = d_in[8];

    int M = in_sizes[0] / DD;       // 100000 nodes
    int E = in_sizes[1] / 2;        // 1600000 edges
    int G = out_size / DD;          // 64 graphs

    char* w = (char*)d_ws;
    auto alloc = [&](size_t bytes)->void*{ void* p = (void*)w; w += (bytes + 255) & ~(size_t)255; return p; };
    int*    flags  = (int*)   alloc(16);
    int*    counts = (int*)   alloc((size_t)M*4);
    int*    rowptr = (int*)   alloc((size_t)(M+1)*4);
    int*    cursor = (int*)   alloc((size_t)M*4);
    int*    bsum   = (int*)   alloc(256*4);
    int*    boff   = (int*)   alloc(256*4);
    float*  dinv   = (float*) alloc((size_t)M*4);
    float*  cntf   = (float*) alloc((size_t)G*4);
    float*  pooled = (float*) alloc((size_t)G*DD*4);
    float*  Wc1    = (float*) alloc(16384*4);
    float*  Wc2    = (float*) alloc(16384*4);
    float*  Wcf    = (float*) alloc(16384*4);
    float*  bc1    = (float*) alloc(128*4);
    float*  bc2    = (float*) alloc(128*4);
    float*  bcf    = (float*) alloc(128*4);
    int*    srcb   = (int*)   alloc((size_t)E*4);
    ushort* Hp     = (ushort*)alloc((size_t)M*DD*2);
    ushort* X2     = (ushort*)alloc((size_t)M*DD*2);
    (void)ws_size; (void)n_in;

    int NB = (M + 1023) / 1024;

    k_detect<<<1, 64, 0, stream>>>(ei, (const ushort*)x, (const ushort*)W1, flags);
    k_canon <<<194, 256, 0, stream>>>(W1, W2, Wfc, b1, b2, bfc,
                                      Wc1, Wc2, Wcf, bc1, bc2, bcf, flags);
    k_init  <<<512, 256, 0, stream>>>(counts, pooled, M, G*DD);
    k_count <<<2048, 256, 0, stream>>>(ei, flags, counts, E);
    k_scan_a<<<NB, 256, 0, stream>>>(counts, bsum, M);
    k_scan_b<<<1, 256, 0, stream>>>(bsum, boff, rowptr, NB, M);
    k_scan_c<<<NB, 256, 0, stream>>>(counts, boff, rowptr, cursor, M);
    k_fill  <<<2048, 256, 0, stream>>>(ei, flags, cursor, srcb, E);
    k_dinv  <<<(M+255)/256, 256, 0, stream>>>(counts, dinv, M);

    // layer 1 (X dtype per flags[1])
    k_gemm  <<<(M+31)/32, 256, 0, stream>>>((const ushort*)x, (const float*)x,
                                            Wc1, dinv, flags, 0, Hp, M);
    k_gather<<<(M+3)/4, 256, 0, stream>>>(Hp, rowptr, srcb, dinv, bc1, X2, M);
    // layer 2 (X2 is always bf16)
    k_gemm  <<<(M+31)/32, 256, 0, stream>>>(X2, (const float*)X2,
                                            Wc2, dinv, flags, 1, Hp, M);
    k_gather<<<(M+3)/4, 256, 0, stream>>>(Hp, rowptr, srcb, dinv, bc2, X2, M);

    // pool + fc
    k_pool<<<(M+255)/256, 256, 0, stream>>>(X2, bat, flags, pooled, M);
    k_cnt <<<(G+63)/64, 64, 0, stream>>>(bat, flags, cntf, M, G);
    k_fc  <<<G, 128, 0, stream>>>(pooled, cntf, Wcf, bcf, flags, (ushort*)d_out, (float*)d_out);
}

// Round 5
// 479.131 us; speedup vs baseline: 1.4798x; 1.2100x over previous
//
#include <hip/hip_runtime.h>
#include <hip/hip_bf16.h>
#include <stdint.h>

typedef unsigned int uint;
typedef unsigned short ushort;

#define DD 128
#define BSHIFT 9          // bucket = 512 consecutive dst nodes
#define NBLK 256          // partition blocks for hist/scat

__device__ __forceinline__ float bf2f(ushort h){ return __uint_as_float(((uint)h)<<16); }
__device__ __forceinline__ ushort f2bf(float f){
    uint u = __float_as_uint(f);
    u += 0x7fffu + ((u>>16)&1u);
    return (ushort)(u>>16);
}

// flags[0]=edge_index is int64, flags[1]=x is bf16, flags[2]=W is bf16
__device__ __forceinline__ int is_bf16_probe(const ushort* p){
    int sane = 0;
    for (int i=0;i<64;i++){
        uint u = p[2*i];
        uint e = (u>>7)&0xffu;
        sane += (e>=90u && e<=160u) ? 1 : 0;
    }
    return sane >= 48;
}
__global__ void k_detect(const int* ei, const ushort* x, const ushort* W1, int* flags){
    if (threadIdx.x==0){
        int ok = 1;
        for (int i=0;i<32;i++) ok &= (ei[2*i+1]==0);
        flags[0] = ok;
        flags[1] = is_bf16_probe(x);
        flags[2] = is_bf16_probe(W1);
    }
}

// canonicalize W1,W2,Wfc (16384 each) + b1,b2,bfc (128 each) to f32
__global__ void k_canon(const void* s0,const void* s1,const void* s2,
                        const void* s3,const void* s4,const void* s5,
                        float* d0,float* d1,float* d2,float* d3,float* d4,float* d5,
                        const int* flags){
    int f = flags[2];
    int i = blockIdx.x*blockDim.x + threadIdx.x;
    const void* s; float* d; int off;
    if (i < 49152){
        int r = i>>14; off = i & 16383;
        s = (r==0)?s0:((r==1)?s1:s2);
        d = (r==0)?d0:((r==1)?d1:d2);
    } else {
        int j = i - 49152; int r = j>>7; off = j & 127;
        if (r >= 3) return;
        s = (r==0)?s3:((r==1)?s4:s5);
        d = (r==0)?d3:((r==1)?d4:d5);
    }
    d[off] = f ? bf2f(((const ushort*)s)[off]) : ((const float*)s)[off];
}

__global__ void k_init(float* pooled, int PM){
    int i = blockIdx.x*blockDim.x + threadIdx.x;
    if (i < PM) pooled[i] = 0.f;
}

// ---- counting-sort CSR build --------------------------------------------
// pass A: per-block bucket histogram (bucket = dst>>9)
__global__ __launch_bounds__(256) void k_hist(const int* __restrict__ ei,
                                              const int* __restrict__ flags,
                                              int* __restrict__ ghist,
                                              int E, int nbuk, int chunk){
    __shared__ int lh[1024];
    int f = flags[0];
    int t = threadIdx.x, b = blockIdx.x;
    for (int i=t;i<nbuk;i+=256) lh[i]=0;
    __syncthreads();
    int e0 = b*chunk, e1 = min(E, e0+chunk);
    for (int e=e0+t; e<e1; e+=256){
        int d = f ? ei[2*(E+e)] : ei[E+e];
        atomicAdd(&lh[d>>BSHIFT],1);
    }
    __syncthreads();
    for (int i=t;i<nbuk;i+=256) ghist[i*NBLK + b] = lh[i];
}

// pass B: exclusive scan of ghist (bucket-major, block-minor) -> gstart
__global__ __launch_bounds__(1024) void k_scanE(const int* __restrict__ ghist,
                                                int* __restrict__ gstart, int total){
    __shared__ int ps[1024];
    int t = threadIdx.x;
    int per = (total + 1023)/1024;
    int i0 = t*per, i1 = min(total, i0+per);
    int s=0;
    for (int i=i0;i<i1;i++) s += ghist[i];
    ps[t]=s; __syncthreads();
    for (int off=1; off<1024; off<<=1){
        int x = (t>=off)? ps[t-off] : 0;
        __syncthreads();
        ps[t]+=x;
        __syncthreads();
    }
    int run = ps[t]-s; // exclusive
    for (int i=i0;i<i1;i++){ gstart[i]=run; run += ghist[i]; }
}

// pass C: scatter (src,dst) pairs into bucket-contiguous regions
__global__ __launch_bounds__(256) void k_scat(const int* __restrict__ ei,
                                              const int* __restrict__ flags,
                                              const int* __restrict__ gstart,
                                              uint2* __restrict__ pairs,
                                              int E, int nbuk, int chunk){
    __shared__ int cur[1024];
    int f = flags[0];
    int t = threadIdx.x, b = blockIdx.x;
    for (int i=t;i<nbuk;i+=256) cur[i] = gstart[i*NBLK + b];
    __syncthreads();
    int e0 = b*chunk, e1 = min(E, e0+chunk);
    for (int e=e0+t; e<e1; e+=256){
        int d = f ? ei[2*(E+e)] : ei[E+e];
        int s = f ? ei[2*e]     : ei[e];
        int p = atomicAdd(&cur[d>>BSHIFT],1);
        pairs[p] = make_uint2((uint)s,(uint)d);
    }
}

// pass D: per-bucket fine CSR: counts -> LDS scan -> rowptr/dinv + srcb scatter
__global__ __launch_bounds__(256) void k_build(const uint2* __restrict__ pairs,
                                               const int* __restrict__ gstart,
                                               int* __restrict__ rowptr,
                                               float* __restrict__ dinv,
                                               int* __restrict__ srcb,
                                               int E, int nbuk, int M){
    __shared__ int cnt[512], off[512], cur[512], ps[256];
    int b = blockIdx.x, t = threadIdx.x;
    int base = gstart[b*NBLK];
    int end  = (b+1<nbuk) ? gstart[(b+1)*NBLK] : E;
    for (int i=t;i<512;i+=256) cnt[i]=0;
    __syncthreads();
    for (int e=base+t; e<end; e+=256){
        uint2 pr = pairs[e];
        atomicAdd(&cnt[pr.y & 511],1);
    }
    __syncthreads();
    int c0 = cnt[2*t], c1 = cnt[2*t+1];
    int s = c0+c1;
    ps[t]=s; __syncthreads();
    for (int o2=1;o2<256;o2<<=1){
        int x=(t>=o2)?ps[t-o2]:0; __syncthreads(); ps[t]+=x; __syncthreads();
    }
    int ex = ps[t]-s;
    off[2*t]=ex;    off[2*t+1]=ex+c0;
    cur[2*t]=ex;    cur[2*t+1]=ex+c0;
    __syncthreads();
    for (int i=t;i<512;i+=256){
        int n = (b<<BSHIFT)+i;
        if (n<M){
            rowptr[n] = base + off[i];
            dinv[n]   = rsqrtf((float)(cnt[i]+1));
        }
    }
    if (b==0 && t==0) rowptr[M] = E;
    for (int e=base+t; e<end; e+=256){
        uint2 pr = pairs[e];
        int i = pr.y & 511;
        int p = atomicAdd(&cur[i],1);
        srcb[base+p] = (int)pr.x;
    }
}
// -------------------------------------------------------------------------

// Hp[n,c] = bf16( dinv[n] * sum_k X[n,k]*Wc[k,c] ); X dtype from flags[1] (or forced bf16)
__global__ __launch_bounds__(256) void k_gemm(const ushort* Xb, const float* Xf,
                                              const float* __restrict__ Wc,
                                              const float* __restrict__ dinv,
                                              const int* __restrict__ flags, int force_bf16,
                                              ushort* __restrict__ Hp, int M){
    __shared__ float Wl[64*128];   // 32 KB
    __shared__ float Xl[32*69];    // 8.8 KB, pad 69 -> conflict-free row reads
    int t = threadIdx.x;
    int n0 = blockIdx.x*32;
    int xbf = force_bf16 ? 1 : flags[1];

    int c4 = (t & 31) * 4;
    int r4 = (t >> 5) * 4;
    float acc[4][4];
    #pragma unroll
    for (int i=0;i<4;i++)
        #pragma unroll
        for (int j=0;j<4;j++) acc[i][j] = 0.f;

    for (int h=0; h<2; ++h){
        {
            const float4* Ws = (const float4*)(Wc + h*64*DD);
            float4* Wd = (float4*)Wl;
            #pragma unroll
            for (int j=0;j<8;j++) Wd[t + j*256] = Ws[t + j*256];
        }
        {
            int r  = t & 31;
            int k0 = (t >> 5) * 8;
            int n = n0 + r;
            float v[8];
            if (n < M){
                if (xbf){
                    const ushort* p = Xb + (size_t)n*DD + h*64 + k0;
                    uint4 a = *(const uint4*)p;
                    uint av[4] = {a.x,a.y,a.z,a.w};
                    #pragma unroll
                    for (int j=0;j<4;j++){
                        v[2*j]   = __uint_as_float(av[j]<<16);
                        v[2*j+1] = __uint_as_float(av[j]&0xffff0000u);
                    }
                } else {
                    const float* p = Xf + (size_t)n*DD + h*64 + k0;
                    float4 a = *(const float4*)p;
                    float4 b = *(const float4*)(p+4);
                    v[0]=a.x; v[1]=a.y; v[2]=a.z; v[3]=a.w;
                    v[4]=b.x; v[5]=b.y; v[6]=b.z; v[7]=b.w;
                }
            } else {
                #pragma unroll
                for (int j=0;j<8;j++) v[j]=0.f;
            }
            float* xd = &Xl[r*69 + k0];
            #pragma unroll
            for (int j=0;j<8;j++) xd[j] = v[j];
        }
        __syncthreads();

        #pragma unroll 4
        for (int k=0;k<64;k++){
            float4 wv = *(const float4*)&Wl[k*DD + c4];
            float a0 = Xl[(r4+0)*69 + k];
            float a1 = Xl[(r4+1)*69 + k];
            float a2 = Xl[(r4+2)*69 + k];
            float a3 = Xl[(r4+3)*69 + k];
            acc[0][0]=fmaf(a0,wv.x,acc[0][0]); acc[0][1]=fmaf(a0,wv.y,acc[0][1]);
            acc[0][2]=fmaf(a0,wv.z,acc[0][2]); acc[0][3]=fmaf(a0,wv.w,acc[0][3]);
            acc[1][0]=fmaf(a1,wv.x,acc[1][0]); acc[1][1]=fmaf(a1,wv.y,acc[1][1]);
            acc[1][2]=fmaf(a1,wv.z,acc[1][2]); acc[1][3]=fmaf(a1,wv.w,acc[1][3]);
            acc[2][0]=fmaf(a2,wv.x,acc[2][0]); acc[2][1]=fmaf(a2,wv.y,acc[2][1]);
            acc[2][2]=fmaf(a2,wv.z,acc[2][2]); acc[2][3]=fmaf(a2,wv.w,acc[2][3]);
            acc[3][0]=fmaf(a3,wv.x,acc[3][0]); acc[3][1]=fmaf(a3,wv.y,acc[3][1]);
            acc[3][2]=fmaf(a3,wv.z,acc[3][2]); acc[3][3]=fmaf(a3,wv.w,acc[3][3]);
        }
        __syncthreads();
    }

    #pragma unroll
    for (int i=0;i<4;i++){
        int n = n0 + r4 + i;
        if (n < M){
            float w = dinv[n];
            uint2 o;
            o.x = (uint)f2bf(acc[i][0]*w) | ((uint)f2bf(acc[i][1]*w)<<16);
            o.y = (uint)f2bf(acc[i][2]*w) | ((uint)f2bf(acc[i][3]*w)<<16);
            *(uint2*)&Hp[(size_t)n*DD + c4] = o;
        }
    }
}

// one wave per node: out[n] = relu( dinv[n]*(Hp[n] + sum_{e} Hp[src]) + bias )
__global__ __launch_bounds__(256) void k_gather(const ushort* __restrict__ Hp,
                                                const int* __restrict__ rowptr,
                                                const int* __restrict__ srcb,
                                                const float* __restrict__ dinv,
                                                const float* __restrict__ bc,
                                                ushort* __restrict__ Xout, int M){
    int wid  = (int)((blockIdx.x*(size_t)blockDim.x + threadIdx.x) >> 6);
    int lane = threadIdx.x & 63;
    if (wid >= M) return;
    const uint* Hp32 = (const uint*)Hp;

    uint v = Hp32[(size_t)wid*64 + lane];            // self-loop
    float a0 = __uint_as_float(v<<16);
    float a1 = __uint_as_float(v & 0xffff0000u);

    int rp  = rowptr[wid];
    int rp1 = rowptr[wid+1];
    while (rp < rp1){
        int m = rp1 - rp; if (m > 64) m = 64;
        int idx = (lane < m) ? srcb[rp + lane] : 0;
        int j = 0;
        for (; j+4 <= m; j += 4){
            int s0 = __shfl(idx, j,   64);
            int s1 = __shfl(idx, j+1, 64);
            int s2 = __shfl(idx, j+2, 64);
            int s3 = __shfl(idx, j+3, 64);
            uint u0 = Hp32[(size_t)s0*64 + lane];
            uint u1 = Hp32[(size_t)s1*64 + lane];
            uint u2 = Hp32[(size_t)s2*64 + lane];
            uint u3 = Hp32[(size_t)s3*64 + lane];
            a0 += __uint_as_float(u0<<16); a1 += __uint_as_float(u0&0xffff0000u);
            a0 += __uint_as_float(u1<<16); a1 += __uint_as_float(u1&0xffff0000u);
            a0 += __uint_as_float(u2<<16); a1 += __uint_as_float(u2&0xffff0000u);
            a0 += __uint_as_float(u3<<16); a1 += __uint_as_float(u3&0xffff0000u);
        }
        for (; j<m; j++){
            int s = __shfl(idx, j, 64);
            uint u = Hp32[(size_t)s*64 + lane];
            a0 += __uint_as_float(u<<16); a1 += __uint_as_float(u&0xffff0000u);
        }
        rp += m;
    }

    float w = dinv[wid];
    float o0 = fmaxf(fmaf(a0, w, bc[2*lane]),   0.f);
    float o1 = fmaxf(fmaf(a1, w, bc[2*lane+1]), 0.f);
    ((uint*)Xout)[(size_t)wid*64 + lane] = (uint)f2bf(o0) | ((uint)f2bf(o1)<<16);
}

// mean-pool numerator (latency-optimized, round-4 version)
__global__ __launch_bounds__(256) void k_pool(const ushort* __restrict__ X3,
                                              const int* __restrict__ batch,
                                              const int* __restrict__ flags,
                                              float* __restrict__ pooled, int M){
    int f = flags[0];
    int t = threadIdx.x;
    int c32 = t & 63;
    int row = t >> 6;
    int n0 = blockIdx.x * 256;
    if (n0 >= M) return;
    int nend = n0 + 256; if (nend > M) nend = M;
    const uint* X3u = (const uint*)X3;

    float a0 = 0.f, a1 = 0.f;
    int cur = -1;

    int n = n0 + row;
    #define POOL_PROC(gg, uu) \
        if ((gg) != cur){ \
            if (cur >= 0){ \
                atomicAdd(&pooled[cur*DD + 2*c32],   a0); \
                atomicAdd(&pooled[cur*DD + 2*c32+1], a1); \
            } \
            a0 = 0.f; a1 = 0.f; cur = (gg); \
        } \
        a0 += __uint_as_float((uu)<<16); \
        a1 += __uint_as_float((uu) & 0xffff0000u);

    for (; n + 12 < nend; n += 16){
        int g0 = f ? batch[2*n]      : batch[n];
        int g1 = f ? batch[2*(n+4)]  : batch[n+4];
        int g2 = f ? batch[2*(n+8)]  : batch[n+8];
        int g3 = f ? batch[2*(n+12)] : batch[n+12];
        uint u0 = X3u[(size_t)n*64      + c32];
        uint u1 = X3u[(size_t)(n+4)*64  + c32];
        uint u2 = X3u[(size_t)(n+8)*64  + c32];
        uint u3 = X3u[(size_t)(n+12)*64 + c32];
        POOL_PROC(g0, u0);
        POOL_PROC(g1, u1);
        POOL_PROC(g2, u2);
        POOL_PROC(g3, u3);
    }
    for (; n < nend; n += 4){
        int g = f ? batch[2*n] : batch[n];
        uint u = X3u[(size_t)n*64 + c32];
        POOL_PROC(g, u);
    }
    #undef POOL_PROC

    if (cur >= 0){
        atomicAdd(&pooled[cur*DD + 2*c32],   a0);
        atomicAdd(&pooled[cur*DD + 2*c32+1], a1);
    }
}

__global__ void k_cnt(const int* __restrict__ batch, const int* __restrict__ flags,
                      float* __restrict__ cntf, int M, int G){
    int f = flags[0];
    int g = blockIdx.x*blockDim.x + threadIdx.x;
    if (g >= G) return;
    int lo = 0, hi = M;
    while (lo < hi){ int mid = (lo+hi)>>1; int bv = f ? batch[2*mid] : batch[mid]; if (bv > g) hi = mid; else lo = mid+1; }
    int ub_g = lo;
    lo = 0; hi = M;
    while (lo < hi){ int mid = (lo+hi)>>1; int bv = f ? batch[2*mid] : batch[mid]; if (bv > g-1) hi = mid; else lo = mid+1; }
    cntf[g] = (float)(ub_g - lo);
}

__global__ void k_fc(const float* __restrict__ pooled, const float* __restrict__ cntf,
                     const float* __restrict__ Wcf, const float* __restrict__ bcf,
                     const int* __restrict__ flags, ushort* out16, float* out32){
    __shared__ float p[128];
    int g = blockIdx.x, c = threadIdx.x;
    p[c] = pooled[g*DD + c] / fmaxf(cntf[g], 1.f);
    __syncthreads();
    float acc = bcf[c];
    #pragma unroll 8
    for (int k=0;k<128;k++) acc = fmaf(p[k], Wcf[k*DD + c], acc);
    float r = fmaxf(acc, 0.f);
    if (flags[1]) out16[g*DD + c] = f2bf(r);
    else          out32[g*DD + c] = r;
}

extern "C" void kernel_launch(void* const* d_in, const int* in_sizes, int n_in,
                              void* d_out, int out_size, void* d_ws, size_t ws_size,
                              hipStream_t stream) {
    const void* x    = d_in[0];
    const int*  ei   = (const int*)d_in[1];
    const int*  bat  = (const int*)d_in[2];
    const void* W1   = d_in[3];
    const void* b1   = d_in[4];
    const void* W2   = d_in[5];
    const void* b2   = d_in[6];
    const void* Wfc  = d_in[7];
    const void* bfc  = d_in[8];

    int M = in_sizes[0] / DD;       // 100000 nodes
    int E = in_sizes[1] / 2;        // 1600000 edges
    int G = out_size / DD;          // 64 graphs
    int nbuk  = (M + 511) >> BSHIFT;        // 196 buckets of 512 dsts
    int chunk = (E + NBLK - 1) / NBLK;

    char* w = (char*)d_ws;
    auto alloc = [&](size_t bytes)->void*{ void* p = (void*)w; w += (bytes + 255) & ~(size_t)255; return p; };
    int*    flags  = (int*)   alloc(16);
    int*    rowptr = (int*)   alloc((size_t)(M+1)*4);
    int*    ghist  = (int*)   alloc((size_t)nbuk*NBLK*4);
    int*    gstart = (int*)   alloc((size_t)nbuk*NBLK*4);
    float*  dinv   = (float*) alloc((size_t)M*4);
    float*  cntf   = (float*) alloc((size_t)G*4);
    float*  pooled = (float*) alloc((size_t)G*DD*4);
    float*  Wc1    = (float*) alloc(16384*4);
    float*  Wc2    = (float*) alloc(16384*4);
    float*  Wcf    = (float*) alloc(16384*4);
    float*  bc1    = (float*) alloc(128*4);
    float*  bc2    = (float*) alloc(128*4);
    float*  bcf    = (float*) alloc(128*4);
    int*    srcb   = (int*)   alloc((size_t)E*4);
    ushort* Hp     = (ushort*)alloc((size_t)M*DD*2);
    ushort* X2     = (ushort*)alloc((size_t)M*DD*2);
    uint2*  pairs  = (uint2*)Hp;   // alias: pairs (E*8B) used only before k_gemm writes Hp
    (void)ws_size; (void)n_in;

    k_detect<<<1, 64, 0, stream>>>(ei, (const ushort*)x, (const ushort*)W1, flags);
    k_canon <<<194, 256, 0, stream>>>(W1, W2, Wfc, b1, b2, bfc,
                                      Wc1, Wc2, Wcf, bc1, bc2, bcf, flags);
    k_init  <<<(G*DD+255)/256, 256, 0, stream>>>(pooled, G*DD);

    // counting-sort CSR build
    k_hist <<<NBLK, 256, 0, stream>>>(ei, flags, ghist, E, nbuk, chunk);
    k_scanE<<<1, 1024, 0, stream>>>(ghist, gstart, nbuk*NBLK);
    k_scat <<<NBLK, 256, 0, stream>>>(ei, flags, gstart, pairs, E, nbuk, chunk);
    k_build<<<nbuk, 256, 0, stream>>>(pairs, gstart, rowptr, dinv, srcb, E, nbuk, M);

    // layer 1 (X dtype per flags[1])
    k_gemm  <<<(M+31)/32, 256, 0, stream>>>((const ushort*)x, (const float*)x,
                                            Wc1, dinv, flags, 0, Hp, M);
    k_gather<<<(M+3)/4, 256, 0, stream>>>(Hp, rowptr, srcb, dinv, bc1, X2, M);
    // layer 2 (X2 is always bf16)
    k_gemm  <<<(M+31)/32, 256, 0, stream>>>(X2, (const float*)X2,
                                            Wc2, dinv, flags, 1, Hp, M);
    k_gather<<<(M+3)/4, 256, 0, stream>>>(Hp, rowptr, srcb, dinv, bc2, X2, M);

    // pool + fc
    k_pool<<<(M+255)/256, 256, 0, stream>>>(X2, bat, flags, pooled, M);
    k_cnt <<<(G+63)/64, 64, 0, stream>>>(bat, flags, cntf, M, G);
    k_fc  <<<G, 128, 0, stream>>>(pooled, cntf, Wcf, bcf, flags, (ushort*)d_out, (float*)d_out);
}

// Round 6
// 408.525 us; speedup vs baseline: 1.7355x; 1.1728x over previous
//
#include <hip/hip_runtime.h>
#include <hip/hip_bf16.h>
#include <stdint.h>

typedef unsigned int uint;
typedef unsigned short ushort;

#define DD 128
#define BSHIFT 9          // bucket = 512 consecutive dst nodes
#define NBLK 256          // partition blocks for hist/scat

__device__ __forceinline__ float bf2f(ushort h){ return __uint_as_float(((uint)h)<<16); }
__device__ __forceinline__ ushort f2bf(float f){
    uint u = __float_as_uint(f);
    u += 0x7fffu + ((u>>16)&1u);
    return (ushort)(u>>16);
}

// flags[0]=edge_index is int64, flags[1]=x is bf16, flags[2]=W is bf16
// one wave, parallel probe (old single-thread version cost ~60 us of serial HBM latency)
__global__ void k_detect(const int* ei, const ushort* x, const ushort* W1, int* flags){
    int t = threadIdx.x;  // 0..63
    unsigned long long b0 = __ballot((t < 32) ? (ei[2*t+1] == 0) : 1);
    uint ex = (((uint)x[2*t])  >> 7) & 0xffu;
    uint ew = (((uint)W1[2*t]) >> 7) & 0xffu;
    unsigned long long b1 = __ballot(ex >= 90u && ex <= 160u);
    unsigned long long b2 = __ballot(ew >= 90u && ew <= 160u);
    if (t == 0){
        flags[0] = (b0 == ~0ull) ? 1 : 0;
        flags[1] = (__popcll(b1) >= 48) ? 1 : 0;
        flags[2] = (__popcll(b2) >= 48) ? 1 : 0;
    }
}

// canonicalize W1,W2,Wfc (16384 each) + b1,b2,bfc (128 each) to f32
__global__ void k_canon(const void* s0,const void* s1,const void* s2,
                        const void* s3,const void* s4,const void* s5,
                        float* d0,float* d1,float* d2,float* d3,float* d4,float* d5,
                        const int* flags){
    int f = flags[2];
    int i = blockIdx.x*blockDim.x + threadIdx.x;
    const void* s; float* d; int off;
    if (i < 49152){
        int r = i>>14; off = i & 16383;
        s = (r==0)?s0:((r==1)?s1:s2);
        d = (r==0)?d0:((r==1)?d1:d2);
    } else {
        int j = i - 49152; int r = j>>7; off = j & 127;
        if (r >= 3) return;
        s = (r==0)?s3:((r==1)?s4:s5);
        d = (r==0)?d3:((r==1)?d4:d5);
    }
    d[off] = f ? bf2f(((const ushort*)s)[off]) : ((const float*)s)[off];
}

__global__ void k_init(float* pooled, int PM, int* buktot, int nbuk){
    int i = blockIdx.x*blockDim.x + threadIdx.x;
    if (i < PM) pooled[i] = 0.f;
    if (i < nbuk) buktot[i] = 0;
}

// ---- counting-sort CSR build --------------------------------------------
// pass A: per-block bucket histogram (bucket = dst>>9) + global bucket totals
__global__ __launch_bounds__(256) void k_hist(const int* __restrict__ ei,
                                              const int* __restrict__ flags,
                                              int* __restrict__ ghist,
                                              int* __restrict__ buktot,
                                              int E, int nbuk, int chunk){
    __shared__ int lh[1024];
    int f = flags[0];
    int t = threadIdx.x, b = blockIdx.x;
    for (int i=t;i<nbuk;i+=256) lh[i]=0;
    __syncthreads();
    int e0 = b*chunk, e1 = min(E, e0+chunk);
    for (int e=e0+t; e<e1; e+=256){
        int d = f ? ei[2*(E+e)] : ei[E+e];
        atomicAdd(&lh[d>>BSHIFT],1);
    }
    __syncthreads();
    for (int i=t;i<nbuk;i+=256){
        int v = lh[i];
        ghist[i*NBLK + b] = v;
        if (v) atomicAdd(&buktot[i], v);
    }
}

// pass B1: scan 196 bucket totals (1 small block — fast because tiny)
__global__ void k_scanB2(const int* __restrict__ buktot, int* __restrict__ bukoff, int nbuk){
    __shared__ int ts[256];
    int t = threadIdx.x;
    int v = (t<nbuk) ? buktot[t] : 0;
    ts[t] = v; __syncthreads();
    for (int off=1; off<256; off<<=1){
        int x = (t>=off) ? ts[t-off] : 0;
        __syncthreads(); ts[t] += x; __syncthreads();
    }
    if (t<nbuk) bukoff[t] = ts[t] - v;   // exclusive
}

// pass B2: per-bucket scan of the 256 block entries -> gstart
__global__ __launch_bounds__(256) void k_apply(const int* __restrict__ ghist,
                                               const int* __restrict__ bukoff,
                                               int* __restrict__ gstart, int nbuk){
    __shared__ int ts[256];
    int b = blockIdx.x, t = threadIdx.x;
    int v = ghist[b*NBLK + t];
    ts[t] = v; __syncthreads();
    for (int off=1; off<256; off<<=1){
        int x = (t>=off) ? ts[t-off] : 0;
        __syncthreads(); ts[t] += x; __syncthreads();
    }
    gstart[b*NBLK + t] = bukoff[b] + ts[t] - v;
}

// pass C: scatter (src,dst) pairs into bucket-contiguous regions
__global__ __launch_bounds__(256) void k_scat(const int* __restrict__ ei,
                                              const int* __restrict__ flags,
                                              const int* __restrict__ gstart,
                                              uint2* __restrict__ pairs,
                                              int E, int nbuk, int chunk){
    __shared__ int cur[1024];
    int f = flags[0];
    int t = threadIdx.x, b = blockIdx.x;
    for (int i=t;i<nbuk;i+=256) cur[i] = gstart[i*NBLK + b];
    __syncthreads();
    int e0 = b*chunk, e1 = min(E, e0+chunk);
    for (int e=e0+t; e<e1; e+=256){
        int d = f ? ei[2*(E+e)] : ei[E+e];
        int s = f ? ei[2*e]     : ei[e];
        int p = atomicAdd(&cur[d>>BSHIFT],1);
        pairs[p] = make_uint2((uint)s,(uint)d);
    }
}

// pass D: per-bucket fine CSR: counts -> LDS scan -> rowptr/dinv + srcb scatter
__global__ __launch_bounds__(256) void k_build(const uint2* __restrict__ pairs,
                                               const int* __restrict__ gstart,
                                               int* __restrict__ rowptr,
                                               float* __restrict__ dinv,
                                               int* __restrict__ srcb,
                                               int E, int nbuk, int M){
    __shared__ int cnt[512], off[512], cur[512], ps[256];
    int b = blockIdx.x, t = threadIdx.x;
    int base = gstart[b*NBLK];
    int end  = (b+1<nbuk) ? gstart[(b+1)*NBLK] : E;
    for (int i=t;i<512;i+=256) cnt[i]=0;
    __syncthreads();
    for (int e=base+t; e<end; e+=256){
        uint2 pr = pairs[e];
        atomicAdd(&cnt[pr.y & 511],1);
    }
    __syncthreads();
    int c0 = cnt[2*t], c1 = cnt[2*t+1];
    int s = c0+c1;
    ps[t]=s; __syncthreads();
    for (int o2=1;o2<256;o2<<=1){
        int x=(t>=o2)?ps[t-o2]:0; __syncthreads(); ps[t]+=x; __syncthreads();
    }
    int ex = ps[t]-s;
    off[2*t]=ex;    off[2*t+1]=ex+c0;
    cur[2*t]=ex;    cur[2*t+1]=ex+c0;
    __syncthreads();
    for (int i=t;i<512;i+=256){
        int n = (b<<BSHIFT)+i;
        if (n<M){
            rowptr[n] = base + off[i];
            dinv[n]   = rsqrtf((float)(cnt[i]+1));
        }
    }
    if (b==0 && t==0) rowptr[M] = E;
    for (int e=base+t; e<end; e+=256){
        uint2 pr = pairs[e];
        int i = pr.y & 511;
        int p = atomicAdd(&cur[i],1);
        srcb[base+p] = (int)pr.x;
    }
}
// -------------------------------------------------------------------------

// Hp[n,c] = bf16( dinv[n] * sum_k X[n,k]*Wc[k,c] ); X dtype from flags[1] (or forced bf16)
__global__ __launch_bounds__(256) void k_gemm(const ushort* Xb, const float* Xf,
                                              const float* __restrict__ Wc,
                                              const float* __restrict__ dinv,
                                              const int* __restrict__ flags, int force_bf16,
                                              ushort* __restrict__ Hp, int M){
    __shared__ float Wl[64*128];   // 32 KB
    __shared__ float Xl[32*69];    // 8.8 KB, pad 69 -> conflict-free row reads
    int t = threadIdx.x;
    int n0 = blockIdx.x*32;
    int xbf = force_bf16 ? 1 : flags[1];

    int c4 = (t & 31) * 4;
    int r4 = (t >> 5) * 4;
    float acc[4][4];
    #pragma unroll
    for (int i=0;i<4;i++)
        #pragma unroll
        for (int j=0;j<4;j++) acc[i][j] = 0.f;

    for (int h=0; h<2; ++h){
        {
            const float4* Ws = (const float4*)(Wc + h*64*DD);
            float4* Wd = (float4*)Wl;
            #pragma unroll
            for (int j=0;j<8;j++) Wd[t + j*256] = Ws[t + j*256];
        }
        {
            int r  = t & 31;
            int k0 = (t >> 5) * 8;
            int n = n0 + r;
            float v[8];
            if (n < M){
                if (xbf){
                    const ushort* p = Xb + (size_t)n*DD + h*64 + k0;
                    uint4 a = *(const uint4*)p;
                    uint av[4] = {a.x,a.y,a.z,a.w};
                    #pragma unroll
                    for (int j=0;j<4;j++){
                        v[2*j]   = __uint_as_float(av[j]<<16);
                        v[2*j+1] = __uint_as_float(av[j]&0xffff0000u);
                    }
                } else {
                    const float* p = Xf + (size_t)n*DD + h*64 + k0;
                    float4 a = *(const float4*)p;
                    float4 b = *(const float4*)(p+4);
                    v[0]=a.x; v[1]=a.y; v[2]=a.z; v[3]=a.w;
                    v[4]=b.x; v[5]=b.y; v[6]=b.z; v[7]=b.w;
                }
            } else {
                #pragma unroll
                for (int j=0;j<8;j++) v[j]=0.f;
            }
            float* xd = &Xl[r*69 + k0];
            #pragma unroll
            for (int j=0;j<8;j++) xd[j] = v[j];
        }
        __syncthreads();

        #pragma unroll 4
        for (int k=0;k<64;k++){
            float4 wv = *(const float4*)&Wl[k*DD + c4];
            float a0 = Xl[(r4+0)*69 + k];
            float a1 = Xl[(r4+1)*69 + k];
            float a2 = Xl[(r4+2)*69 + k];
            float a3 = Xl[(r4+3)*69 + k];
            acc[0][0]=fmaf(a0,wv.x,acc[0][0]); acc[0][1]=fmaf(a0,wv.y,acc[0][1]);
            acc[0][2]=fmaf(a0,wv.z,acc[0][2]); acc[0][3]=fmaf(a0,wv.w,acc[0][3]);
            acc[1][0]=fmaf(a1,wv.x,acc[1][0]); acc[1][1]=fmaf(a1,wv.y,acc[1][1]);
            acc[1][2]=fmaf(a1,wv.z,acc[1][2]); acc[1][3]=fmaf(a1,wv.w,acc[1][3]);
            acc[2][0]=fmaf(a2,wv.x,acc[2][0]); acc[2][1]=fmaf(a2,wv.y,acc[2][1]);
            acc[2][2]=fmaf(a2,wv.z,acc[2][2]); acc[2][3]=fmaf(a2,wv.w,acc[2][3]);
            acc[3][0]=fmaf(a3,wv.x,acc[3][0]); acc[3][1]=fmaf(a3,wv.y,acc[3][1]);
            acc[3][2]=fmaf(a3,wv.z,acc[3][2]); acc[3][3]=fmaf(a3,wv.w,acc[3][3]);
        }
        __syncthreads();
    }

    #pragma unroll
    for (int i=0;i<4;i++){
        int n = n0 + r4 + i;
        if (n < M){
            float w = dinv[n];
            uint2 o;
            o.x = (uint)f2bf(acc[i][0]*w) | ((uint)f2bf(acc[i][1]*w)<<16);
            o.y = (uint)f2bf(acc[i][2]*w) | ((uint)f2bf(acc[i][3]*w)<<16);
            *(uint2*)&Hp[(size_t)n*DD + c4] = o;
        }
    }
}

// one wave per node: out[n] = relu( dinv[n]*(Hp[n] + sum_{e} Hp[src]) + bias )
__global__ __launch_bounds__(256) void k_gather(const ushort* __restrict__ Hp,
                                                const int* __restrict__ rowptr,
                                                const int* __restrict__ srcb,
                                                const float* __restrict__ dinv,
                                                const float* __restrict__ bc,
                                                ushort* __restrict__ Xout, int M){
    int wid  = (int)((blockIdx.x*(size_t)blockDim.x + threadIdx.x) >> 6);
    int lane = threadIdx.x & 63;
    if (wid >= M) return;
    const uint* Hp32 = (const uint*)Hp;

    uint v = Hp32[(size_t)wid*64 + lane];            // self-loop
    float a0 = __uint_as_float(v<<16);
    float a1 = __uint_as_float(v & 0xffff0000u);

    int rp  = rowptr[wid];
    int rp1 = rowptr[wid+1];
    while (rp < rp1){
        int m = rp1 - rp; if (m > 64) m = 64;
        int idx = (lane < m) ? srcb[rp + lane] : 0;
        int j = 0;
        for (; j+4 <= m; j += 4){
            int s0 = __shfl(idx, j,   64);
            int s1 = __shfl(idx, j+1, 64);
            int s2 = __shfl(idx, j+2, 64);
            int s3 = __shfl(idx, j+3, 64);
            uint u0 = Hp32[(size_t)s0*64 + lane];
            uint u1 = Hp32[(size_t)s1*64 + lane];
            uint u2 = Hp32[(size_t)s2*64 + lane];
            uint u3 = Hp32[(size_t)s3*64 + lane];
            a0 += __uint_as_float(u0<<16); a1 += __uint_as_float(u0&0xffff0000u);
            a0 += __uint_as_float(u1<<16); a1 += __uint_as_float(u1&0xffff0000u);
            a0 += __uint_as_float(u2<<16); a1 += __uint_as_float(u2&0xffff0000u);
            a0 += __uint_as_float(u3<<16); a1 += __uint_as_float(u3&0xffff0000u);
        }
        for (; j<m; j++){
            int s = __shfl(idx, j, 64);
            uint u = Hp32[(size_t)s*64 + lane];
            a0 += __uint_as_float(u<<16); a1 += __uint_as_float(u&0xffff0000u);
        }
        rp += m;
    }

    float w = dinv[wid];
    float o0 = fmaxf(fmaf(a0, w, bc[2*lane]),   0.f);
    float o1 = fmaxf(fmaf(a1, w, bc[2*lane+1]), 0.f);
    ((uint*)Xout)[(size_t)wid*64 + lane] = (uint)f2bf(o0) | ((uint)f2bf(o1)<<16);
}

// mean-pool numerator (latency-optimized, round-4 version)
__global__ __launch_bounds__(256) void k_pool(const ushort* __restrict__ X3,
                                              const int* __restrict__ batch,
                                              const int* __restrict__ flags,
                                              float* __restrict__ pooled, int M){
    int f = flags[0];
    int t = threadIdx.x;
    int c32 = t & 63;
    int row = t >> 6;
    int n0 = blockIdx.x * 256;
    if (n0 >= M) return;
    int nend = n0 + 256; if (nend > M) nend = M;
    const uint* X3u = (const uint*)X3;

    float a0 = 0.f, a1 = 0.f;
    int cur = -1;

    int n = n0 + row;
    #define POOL_PROC(gg, uu) \
        if ((gg) != cur){ \
            if (cur >= 0){ \
                atomicAdd(&pooled[cur*DD + 2*c32],   a0); \
                atomicAdd(&pooled[cur*DD + 2*c32+1], a1); \
            } \
            a0 = 0.f; a1 = 0.f; cur = (gg); \
        } \
        a0 += __uint_as_float((uu)<<16); \
        a1 += __uint_as_float((uu) & 0xffff0000u);

    for (; n + 12 < nend; n += 16){
        int g0 = f ? batch[2*n]      : batch[n];
        int g1 = f ? batch[2*(n+4)]  : batch[n+4];
        int g2 = f ? batch[2*(n+8)]  : batch[n+8];
        int g3 = f ? batch[2*(n+12)] : batch[n+12];
        uint u0 = X3u[(size_t)n*64      + c32];
        uint u1 = X3u[(size_t)(n+4)*64  + c32];
        uint u2 = X3u[(size_t)(n+8)*64  + c32];
        uint u3 = X3u[(size_t)(n+12)*64 + c32];
        POOL_PROC(g0, u0);
        POOL_PROC(g1, u1);
        POOL_PROC(g2, u2);
        POOL_PROC(g3, u3);
    }
    for (; n < nend; n += 4){
        int g = f ? batch[2*n] : batch[n];
        uint u = X3u[(size_t)n*64 + c32];
        POOL_PROC(g, u);
    }
    #undef POOL_PROC

    if (cur >= 0){
        atomicAdd(&pooled[cur*DD + 2*c32],   a0);
        atomicAdd(&pooled[cur*DD + 2*c32+1], a1);
    }
}

__global__ void k_cnt(const int* __restrict__ batch, const int* __restrict__ flags,
                      float* __restrict__ cntf, int M, int G){
    int f = flags[0];
    int g = blockIdx.x*blockDim.x + threadIdx.x;
    if (g >= G) return;
    int lo = 0, hi = M;
    while (lo < hi){ int mid = (lo+hi)>>1; int bv = f ? batch[2*mid] : batch[mid]; if (bv > g) hi = mid; else lo = mid+1; }
    int ub_g = lo;
    lo = 0; hi = M;
    while (lo < hi){ int mid = (lo+hi)>>1; int bv = f ? batch[2*mid] : batch[mid]; if (bv > g-1) hi = mid; else lo = mid+1; }
    cntf[g] = (float)(ub_g - lo);
}

__global__ void k_fc(const float* __restrict__ pooled, const float* __restrict__ cntf,
                     const float* __restrict__ Wcf, const float* __restrict__ bcf,
                     const int* __restrict__ flags, ushort* out16, float* out32){
    __shared__ float p[128];
    int g = blockIdx.x, c = threadIdx.x;
    p[c] = pooled[g*DD + c] / fmaxf(cntf[g], 1.f);
    __syncthreads();
    float acc = bcf[c];
    #pragma unroll 8
    for (int k=0;k<128;k++) acc = fmaf(p[k], Wcf[k*DD + c], acc);
    float r = fmaxf(acc, 0.f);
    if (flags[1]) out16[g*DD + c] = f2bf(r);
    else          out32[g*DD + c] = r;
}

extern "C" void kernel_launch(void* const* d_in, const int* in_sizes, int n_in,
                              void* d_out, int out_size, void* d_ws, size_t ws_size,
                              hipStream_t stream) {
    const void* x    = d_in[0];
    const int*  ei   = (const int*)d_in[1];
    const int*  bat  = (const int*)d_in[2];
    const void* W1   = d_in[3];
    const void* b1   = d_in[4];
    const void* W2   = d_in[5];
    const void* b2   = d_in[6];
    const void* Wfc  = d_in[7];
    const void* bfc  = d_in[8];

    int M = in_sizes[0] / DD;       // 100000 nodes
    int E = in_sizes[1] / 2;        // 1600000 edges
    int G = out_size / DD;          // 64 graphs
    int nbuk  = (M + 511) >> BSHIFT;        // 196 buckets of 512 dsts
    int chunk = (E + NBLK - 1) / NBLK;

    char* w = (char*)d_ws;
    auto alloc = [&](size_t bytes)->void*{ void* p = (void*)w; w += (bytes + 255) & ~(size_t)255; return p; };
    int*    flags  = (int*)   alloc(16);
    int*    rowptr = (int*)   alloc((size_t)(M+1)*4);
    int*    ghist  = (int*)   alloc((size_t)nbuk*NBLK*4);
    int*    gstart = (int*)   alloc((size_t)nbuk*NBLK*4);
    int*    buktot = (int*)   alloc((size_t)nbuk*4);
    int*    bukoff = (int*)   alloc((size_t)nbuk*4);
    float*  dinv   = (float*) alloc((size_t)M*4);
    float*  cntf   = (float*) alloc((size_t)G*4);
    float*  pooled = (float*) alloc((size_t)G*DD*4);
    float*  Wc1    = (float*) alloc(16384*4);
    float*  Wc2    = (float*) alloc(16384*4);
    float*  Wcf    = (float*) alloc(16384*4);
    float*  bc1    = (float*) alloc(128*4);
    float*  bc2    = (float*) alloc(128*4);
    float*  bcf    = (float*) alloc(128*4);
    int*    srcb   = (int*)   alloc((size_t)E*4);
    ushort* Hp     = (ushort*)alloc((size_t)M*DD*2);
    ushort* X2     = (ushort*)alloc((size_t)M*DD*2);
    uint2*  pairs  = (uint2*)Hp;   // alias: pairs (E*8B) used only before k_gemm writes Hp
    (void)ws_size; (void)n_in;

    k_detect<<<1, 64, 0, stream>>>(ei, (const ushort*)x, (const ushort*)W1, flags);
    k_canon <<<194, 256, 0, stream>>>(W1, W2, Wfc, b1, b2, bfc,
                                      Wc1, Wc2, Wcf, bc1, bc2, bcf, flags);
    k_init  <<<(G*DD+255)/256, 256, 0, stream>>>(pooled, G*DD, buktot, nbuk);

    // counting-sort CSR build (hierarchical scan: 196-entry top + per-bucket 256)
    k_hist  <<<NBLK, 256, 0, stream>>>(ei, flags, ghist, buktot, E, nbuk, chunk);
    k_scanB2<<<1, 256, 0, stream>>>(buktot, bukoff, nbuk);
    k_apply <<<nbuk, 256, 0, stream>>>(ghist, bukoff, gstart, nbuk);
    k_scat  <<<NBLK, 256, 0, stream>>>(ei, flags, gstart, pairs, E, nbuk, chunk);
    k_build <<<nbuk, 256, 0, stream>>>(pairs, gstart, rowptr, dinv, srcb, E, nbuk, M);

    // layer 1 (X dtype per flags[1])
    k_gemm  <<<(M+31)/32, 256, 0, stream>>>((const ushort*)x, (const float*)x,
                                            Wc1, dinv, flags, 0, Hp, M);
    k_gather<<<(M+3)/4, 256, 0, stream>>>(Hp, rowptr, srcb, dinv, bc1, X2, M);
    // layer 2 (X2 is always bf16)
    k_gemm  <<<(M+31)/32, 256, 0, stream>>>(X2, (const float*)X2,
                                            Wc2, dinv, flags, 1, Hp, M);
    k_gather<<<(M+3)/4, 256, 0, stream>>>(Hp, rowptr, srcb, dinv, bc2, X2, M);

    // pool + fc
    k_pool<<<(M+255)/256, 256, 0, stream>>>(X2, bat, flags, pooled, M);
    k_cnt <<<(G+63)/64, 64, 0, stream>>>(bat, flags, cntf, M, G);
    k_fc  <<<G, 128, 0, stream>>>(pooled, cntf, Wcf, bcf, flags, (ushort*)d_out, (float*)d_out);
}

// Round 7
// 354.511 us; speedup vs baseline: 1.9999x; 1.1524x over previous
//
#include <hip/hip_runtime.h>
#include <hip/hip_bf16.h>
#include <stdint.h>

typedef unsigned int uint;
typedef unsigned short ushort;
typedef __attribute__((ext_vector_type(8))) short short8;
typedef __attribute__((ext_vector_type(4))) float floatx4;

#define DD 128
#define BSHIFT 9          // bucket = 512 consecutive dst nodes
#define NBLK 256          // partition blocks for hist/scat

__device__ __forceinline__ float bf2f(ushort h){ return __uint_as_float(((uint)h)<<16); }
__device__ __forceinline__ ushort f2bf(float f){
    uint u = __float_as_uint(f);
    u += 0x7fffu + ((u>>16)&1u);
    return (ushort)(u>>16);
}

// flags[0]=edge_index is int64, flags[1]=x is bf16, flags[2]=W is bf16
__global__ void k_detect(const int* ei, const ushort* x, const ushort* W1, int* flags){
    int t = threadIdx.x;  // 0..63
    unsigned long long b0 = __ballot((t < 32) ? (ei[2*t+1] == 0) : 1);
    uint ex = (((uint)x[2*t])  >> 7) & 0xffu;
    uint ew = (((uint)W1[2*t]) >> 7) & 0xffu;
    unsigned long long b1 = __ballot(ex >= 90u && ex <= 160u);
    unsigned long long b2 = __ballot(ew >= 90u && ew <= 160u);
    if (t == 0){
        flags[0] = (b0 == ~0ull) ? 1 : 0;
        flags[1] = (__popcll(b1) >= 48) ? 1 : 0;
        flags[2] = (__popcll(b2) >= 48) ? 1 : 0;
    }
}

// canonicalize W1,W2,Wfc (+biases) to f32; additionally W1,W2 -> frag-major bf16
// frag-major for mfma_f32_16x16x32_bf16 B-operand:
//   W[k][n]: c=n>>4, nn=n&15, kk=k>>5, q=(k>>3)&3, j=k&7
//   dest ushort idx = ((c*4+kk)*64 + q*16 + nn)*8 + j
__global__ void k_canon(const void* s0,const void* s1,const void* s2,
                        const void* s3,const void* s4,const void* s5,
                        float* d0,float* d1,float* d2,float* d3,float* d4,float* d5,
                        ushort* wb1, ushort* wb2,
                        const int* flags){
    int f = flags[2];
    int i = blockIdx.x*blockDim.x + threadIdx.x;
    const void* s; float* d; int off; int r;
    if (i < 49152){
        r = i>>14; off = i & 16383;
        s = (r==0)?s0:((r==1)?s1:s2);
        d = (r==0)?d0:((r==1)?d1:d2);
    } else {
        int j = i - 49152; r = j>>7; off = j & 127;
        if (r >= 3) return;
        s = (r==0)?s3:((r==1)?s4:s5);
        d = (r==0)?d3:((r==1)?d4:d5);
        d[off] = f ? bf2f(((const ushort*)s)[off]) : ((const float*)s)[off];
        return;
    }
    float val = f ? bf2f(((const ushort*)s)[off]) : ((const float*)s)[off];
    d[off] = val;
    if (r < 2){
        int k = off>>7, n = off&127;
        int c = n>>4, nn = n&15, kk = k>>5, q = (k>>3)&3, j = k&7;
        ushort* wb = (r==0) ? wb1 : wb2;
        wb[((c*4+kk)*64 + q*16 + nn)*8 + j] = f2bf(val);
    }
}

__global__ void k_init(float* pooled, int PM, int* buktot, int nbuk){
    int i = blockIdx.x*blockDim.x + threadIdx.x;
    if (i < PM) pooled[i] = 0.f;
    if (i < nbuk) buktot[i] = 0;
}

// ---- counting-sort CSR build --------------------------------------------
__global__ __launch_bounds__(256) void k_hist(const int* __restrict__ ei,
                                              const int* __restrict__ flags,
                                              int* __restrict__ ghist,
                                              int* __restrict__ buktot,
                                              int E, int nbuk, int chunk){
    __shared__ int lh[1024];
    int f = flags[0];
    int t = threadIdx.x, b = blockIdx.x;
    for (int i=t;i<nbuk;i+=256) lh[i]=0;
    __syncthreads();
    int e0 = b*chunk, e1 = min(E, e0+chunk);
    for (int e=e0+t; e<e1; e+=256){
        int d = f ? ei[2*(E+e)] : ei[E+e];
        atomicAdd(&lh[d>>BSHIFT],1);
    }
    __syncthreads();
    for (int i=t;i<nbuk;i+=256){
        int v = lh[i];
        ghist[i*NBLK + b] = v;
        if (v) atomicAdd(&buktot[i], v);
    }
}

__global__ void k_scanB2(const int* __restrict__ buktot, int* __restrict__ bukoff, int nbuk){
    __shared__ int ts[256];
    int t = threadIdx.x;
    int v = (t<nbuk) ? buktot[t] : 0;
    ts[t] = v; __syncthreads();
    for (int off=1; off<256; off<<=1){
        int x = (t>=off) ? ts[t-off] : 0;
        __syncthreads(); ts[t] += x; __syncthreads();
    }
    if (t<nbuk) bukoff[t] = ts[t] - v;   // exclusive
}

__global__ __launch_bounds__(256) void k_apply(const int* __restrict__ ghist,
                                               const int* __restrict__ bukoff,
                                               int* __restrict__ gstart, int nbuk){
    __shared__ int ts[256];
    int b = blockIdx.x, t = threadIdx.x;
    int v = ghist[b*NBLK + t];
    ts[t] = v; __syncthreads();
    for (int off=1; off<256; off<<=1){
        int x = (t>=off) ? ts[t-off] : 0;
        __syncthreads(); ts[t] += x; __syncthreads();
    }
    gstart[b*NBLK + t] = bukoff[b] + ts[t] - v;
}

__global__ __launch_bounds__(256) void k_scat(const int* __restrict__ ei,
                                              const int* __restrict__ flags,
                                              const int* __restrict__ gstart,
                                              uint2* __restrict__ pairs,
                                              int E, int nbuk, int chunk){
    __shared__ int cur[1024];
    int f = flags[0];
    int t = threadIdx.x, b = blockIdx.x;
    for (int i=t;i<nbuk;i+=256) cur[i] = gstart[i*NBLK + b];
    __syncthreads();
    int e0 = b*chunk, e1 = min(E, e0+chunk);
    for (int e=e0+t; e<e1; e+=256){
        int d = f ? ei[2*(E+e)] : ei[E+e];
        int s = f ? ei[2*e]     : ei[e];
        int p = atomicAdd(&cur[d>>BSHIFT],1);
        pairs[p] = make_uint2((uint)s,(uint)d);
    }
}

__global__ __launch_bounds__(256) void k_build(const uint2* __restrict__ pairs,
                                               const int* __restrict__ gstart,
                                               int* __restrict__ rowptr,
                                               float* __restrict__ dinv,
                                               int* __restrict__ srcb,
                                               int E, int nbuk, int M){
    __shared__ int cnt[512], off[512], cur[512], ps[256];
    int b = blockIdx.x, t = threadIdx.x;
    int base = gstart[b*NBLK];
    int end  = (b+1<nbuk) ? gstart[(b+1)*NBLK] : E;
    for (int i=t;i<512;i+=256) cnt[i]=0;
    __syncthreads();
    for (int e=base+t; e<end; e+=256){
        uint2 pr = pairs[e];
        atomicAdd(&cnt[pr.y & 511],1);
    }
    __syncthreads();
    int c0 = cnt[2*t], c1 = cnt[2*t+1];
    int s = c0+c1;
    ps[t]=s; __syncthreads();
    for (int o2=1;o2<256;o2<<=1){
        int x=(t>=o2)?ps[t-o2]:0; __syncthreads(); ps[t]+=x; __syncthreads();
    }
    int ex = ps[t]-s;
    off[2*t]=ex;    off[2*t+1]=ex+c0;
    cur[2*t]=ex;    cur[2*t+1]=ex+c0;
    __syncthreads();
    for (int i=t;i<512;i+=256){
        int n = (b<<BSHIFT)+i;
        if (n<M){
            rowptr[n] = base + off[i];
            dinv[n]   = rsqrtf((float)(cnt[i]+1));
        }
    }
    if (b==0 && t==0) rowptr[M] = E;
    for (int e=base+t; e<end; e+=256){
        uint2 pr = pairs[e];
        int i = pr.y & 511;
        int p = atomicAdd(&cur[i],1);
        srcb[base+p] = (int)pr.x;
    }
}
// -------------------------------------------------------------------------

// MFMA GEMM: Hp[n,c] = bf16( dinv[n] * sum_k X[n,k]*W[k,c] )
// block = 64 rows x 128 cols; 4 waves; wave = 16 rows, 8 col-tiles, K-loop of 4.
// LDS operands frag-major: every A/B read is conflict-free ds_read_b128 at base+lane*16.
__global__ __launch_bounds__(256) void k_gemm(const ushort* __restrict__ Xb,
                                              const float* __restrict__ Xf,
                                              const ushort* __restrict__ Wb,  // frag-major bf16
                                              const float* __restrict__ dinv,
                                              const int* __restrict__ flags, int force_bf16,
                                              ushort* __restrict__ Hp, int M){
    __shared__ uint4 Xs4[1024];   // [w][kk][lane] 16 KB
    __shared__ uint4 Ws4[2048];   // [c][kk][lane] 32 KB
    int t = threadIdx.x;
    int n0 = blockIdx.x*64;
    int xbf = force_bf16 ? 1 : flags[1];

    // stage W: straight uint4 copy (frag-major precomputed in k_canon)
    {
        const uint4* sW = (const uint4*)Wb;
        #pragma unroll
        for (int j=0;j<8;j++) Ws4[t + j*256] = sW[t + j*256];
    }
    // stage X as bf16 frags: 1024 chunks; chunk u -> (row=u>>4, kk=(u>>2)&3, q=u&3)
    #pragma unroll
    for (int g=0; g<4; g++){
        int u = g*256 + t;
        int row = u>>4, kk = (u>>2)&3, q = u&3;
        int n = n0 + row;
        uint4 o;
        if (n < M){
            if (xbf){
                o = *(const uint4*)(Xb + (size_t)n*DD + kk*32 + q*8);
            } else {
                const float* p = Xf + (size_t)n*DD + kk*32 + q*8;
                float4 a = *(const float4*)p;
                float4 b = *(const float4*)(p+4);
                o.x = (uint)f2bf(a.x) | ((uint)f2bf(a.y)<<16);
                o.y = (uint)f2bf(a.z) | ((uint)f2bf(a.w)<<16);
                o.z = (uint)f2bf(b.x) | ((uint)f2bf(b.y)<<16);
                o.w = (uint)f2bf(b.z) | ((uint)f2bf(b.w)<<16);
            }
        } else { o = make_uint4(0,0,0,0); }
        int w = row>>4, m16 = row&15;
        Xs4[(w*4+kk)*64 + q*16 + m16] = o;
    }
    __syncthreads();

    int wv = t>>6, lane = t&63;
    const ushort* Xs = (const ushort*)Xs4;
    const ushort* Ws = (const ushort*)Ws4;

    floatx4 acc[8];
    #pragma unroll
    for (int c=0;c<8;c++) acc[c] = (floatx4){0.f,0.f,0.f,0.f};

    #pragma unroll
    for (int kk=0;kk<4;kk++){
        short8 af = *(const short8*)(Xs + ((size_t)((wv*4+kk)*64 + lane))*8);
        #pragma unroll
        for (int c=0;c<8;c++){
            short8 bf = *(const short8*)(Ws + ((size_t)((c*4+kk)*64 + lane))*8);
            acc[c] = __builtin_amdgcn_mfma_f32_16x16x32_bf16(af, bf, acc[c], 0, 0, 0);
        }
    }

    // epilogue: D[row=quad*4+r][col=lane&15]
    int quad = lane>>4, col = lane&15;
    int rbase = n0 + wv*16 + quad*4;
    float dv[4];
    #pragma unroll
    for (int r=0;r<4;r++) dv[r] = (rbase + r < M) ? dinv[rbase + r] : 0.f;
    #pragma unroll
    for (int c=0;c<8;c++){
        #pragma unroll
        for (int r=0;r<4;r++){
            int gn = rbase + r;
            if (gn < M) Hp[(size_t)gn*DD + c*16 + col] = f2bf(acc[c][r]*dv[r]);
        }
    }
}

// one wave per node: out[n] = relu( dinv[n]*(Hp[n] + sum_{e} Hp[src]) + bias )
__global__ __launch_bounds__(256) void k_gather(const ushort* __restrict__ Hp,
                                                const int* __restrict__ rowptr,
                                                const int* __restrict__ srcb,
                                                const float* __restrict__ dinv,
                                                const float* __restrict__ bc,
                                                ushort* __restrict__ Xout, int M){
    int wid  = (int)((blockIdx.x*(size_t)blockDim.x + threadIdx.x) >> 6);
    int lane = threadIdx.x & 63;
    if (wid >= M) return;
    const uint* Hp32 = (const uint*)Hp;

    uint v = Hp32[(size_t)wid*64 + lane];            // self-loop
    float a0 = __uint_as_float(v<<16);
    float a1 = __uint_as_float(v & 0xffff0000u);

    int rp  = rowptr[wid];
    int rp1 = rowptr[wid+1];
    while (rp < rp1){
        int m = rp1 - rp; if (m > 64) m = 64;
        int idx = (lane < m) ? srcb[rp + lane] : 0;
        int j = 0;
        for (; j+4 <= m; j += 4){
            int s0 = __shfl(idx, j,   64);
            int s1 = __shfl(idx, j+1, 64);
            int s2 = __shfl(idx, j+2, 64);
            int s3 = __shfl(idx, j+3, 64);
            uint u0 = Hp32[(size_t)s0*64 + lane];
            uint u1 = Hp32[(size_t)s1*64 + lane];
            uint u2 = Hp32[(size_t)s2*64 + lane];
            uint u3 = Hp32[(size_t)s3*64 + lane];
            a0 += __uint_as_float(u0<<16); a1 += __uint_as_float(u0&0xffff0000u);
            a0 += __uint_as_float(u1<<16); a1 += __uint_as_float(u1&0xffff0000u);
            a0 += __uint_as_float(u2<<16); a1 += __uint_as_float(u2&0xffff0000u);
            a0 += __uint_as_float(u3<<16); a1 += __uint_as_float(u3&0xffff0000u);
        }
        for (; j<m; j++){
            int s = __shfl(idx, j, 64);
            uint u = Hp32[(size_t)s*64 + lane];
            a0 += __uint_as_float(u<<16); a1 += __uint_as_float(u&0xffff0000u);
        }
        rp += m;
    }

    float w = dinv[wid];
    float o0 = fmaxf(fmaf(a0, w, bc[2*lane]),   0.f);
    float o1 = fmaxf(fmaf(a1, w, bc[2*lane+1]), 0.f);
    ((uint*)Xout)[(size_t)wid*64 + lane] = (uint)f2bf(o0) | ((uint)f2bf(o1)<<16);
}

// mean-pool numerator (latency-optimized)
__global__ __launch_bounds__(256) void k_pool(const ushort* __restrict__ X3,
                                              const int* __restrict__ batch,
                                              const int* __restrict__ flags,
                                              float* __restrict__ pooled, int M){
    int f = flags[0];
    int t = threadIdx.x;
    int c32 = t & 63;
    int row = t >> 6;
    int n0 = blockIdx.x * 256;
    if (n0 >= M) return;
    int nend = n0 + 256; if (nend > M) nend = M;
    const uint* X3u = (const uint*)X3;

    float a0 = 0.f, a1 = 0.f;
    int cur = -1;

    int n = n0 + row;
    #define POOL_PROC(gg, uu) \
        if ((gg) != cur){ \
            if (cur >= 0){ \
                atomicAdd(&pooled[cur*DD + 2*c32],   a0); \
                atomicAdd(&pooled[cur*DD + 2*c32+1], a1); \
            } \
            a0 = 0.f; a1 = 0.f; cur = (gg); \
        } \
        a0 += __uint_as_float((uu)<<16); \
        a1 += __uint_as_float((uu) & 0xffff0000u);

    for (; n + 12 < nend; n += 16){
        int g0 = f ? batch[2*n]      : batch[n];
        int g1 = f ? batch[2*(n+4)]  : batch[n+4];
        int g2 = f ? batch[2*(n+8)]  : batch[n+8];
        int g3 = f ? batch[2*(n+12)] : batch[n+12];
        uint u0 = X3u[(size_t)n*64      + c32];
        uint u1 = X3u[(size_t)(n+4)*64  + c32];
        uint u2 = X3u[(size_t)(n+8)*64  + c32];
        uint u3 = X3u[(size_t)(n+12)*64 + c32];
        POOL_PROC(g0, u0);
        POOL_PROC(g1, u1);
        POOL_PROC(g2, u2);
        POOL_PROC(g3, u3);
    }
    for (; n < nend; n += 4){
        int g = f ? batch[2*n] : batch[n];
        uint u = X3u[(size_t)n*64 + c32];
        POOL_PROC(g, u);
    }
    #undef POOL_PROC

    if (cur >= 0){
        atomicAdd(&pooled[cur*DD + 2*c32],   a0);
        atomicAdd(&pooled[cur*DD + 2*c32+1], a1);
    }
}

__global__ void k_cnt(const int* __restrict__ batch, const int* __restrict__ flags,
                      float* __restrict__ cntf, int M, int G){
    int f = flags[0];
    int g = blockIdx.x*blockDim.x + threadIdx.x;
    if (g >= G) return;
    int lo = 0, hi = M;
    while (lo < hi){ int mid = (lo+hi)>>1; int bv = f ? batch[2*mid] : batch[mid]; if (bv > g) hi = mid; else lo = mid+1; }
    int ub_g = lo;
    lo = 0; hi = M;
    while (lo < hi){ int mid = (lo+hi)>>1; int bv = f ? batch[2*mid] : batch[mid]; if (bv > g-1) hi = mid; else lo = mid+1; }
    cntf[g] = (float)(ub_g - lo);
}

__global__ void k_fc(const float* __restrict__ pooled, const float* __restrict__ cntf,
                     const float* __restrict__ Wcf, const float* __restrict__ bcf,
                     const int* __restrict__ flags, ushort* out16, float* out32){
    __shared__ float p[128];
    int g = blockIdx.x, c = threadIdx.x;
    p[c] = pooled[g*DD + c] / fmaxf(cntf[g], 1.f);
    __syncthreads();
    float acc = bcf[c];
    #pragma unroll 8
    for (int k=0;k<128;k++) acc = fmaf(p[k], Wcf[k*DD + c], acc);
    float r = fmaxf(acc, 0.f);
    if (flags[1]) out16[g*DD + c] = f2bf(r);
    else          out32[g*DD + c] = r;
}

extern "C" void kernel_launch(void* const* d_in, const int* in_sizes, int n_in,
                              void* d_out, int out_size, void* d_ws, size_t ws_size,
                              hipStream_t stream) {
    const void* x    = d_in[0];
    const int*  ei   = (const int*)d_in[1];
    const int*  bat  = (const int*)d_in[2];
    const void* W1   = d_in[3];
    const void* b1   = d_in[4];
    const void* W2   = d_in[5];
    const void* b2   = d_in[6];
    const void* Wfc  = d_in[7];
    const void* bfc  = d_in[8];

    int M = in_sizes[0] / DD;       // 100000 nodes
    int E = in_sizes[1] / 2;        // 1600000 edges
    int G = out_size / DD;          // 64 graphs
    int nbuk  = (M + 511) >> BSHIFT;        // 196 buckets of 512 dsts
    int chunk = (E + NBLK - 1) / NBLK;

    char* w = (char*)d_ws;
    auto alloc = [&](size_t bytes)->void*{ void* p = (void*)w; w += (bytes + 255) & ~(size_t)255; return p; };
    int*    flags  = (int*)   alloc(16);
    int*    rowptr = (int*)   alloc((size_t)(M+1)*4);
    int*    ghist  = (int*)   alloc((size_t)nbuk*NBLK*4);
    int*    gstart = (int*)   alloc((size_t)nbuk*NBLK*4);
    int*    buktot = (int*)   alloc((size_t)nbuk*4);
    int*    bukoff = (int*)   alloc((size_t)nbuk*4);
    float*  dinv   = (float*) alloc((size_t)M*4);
    float*  cntf   = (float*) alloc((size_t)G*4);
    float*  pooled = (float*) alloc((size_t)G*DD*4);
    float*  Wc1    = (float*) alloc(16384*4);
    float*  Wc2    = (float*) alloc(16384*4);
    float*  Wcf    = (float*) alloc(16384*4);
    float*  bc1    = (float*) alloc(128*4);
    float*  bc2    = (float*) alloc(128*4);
    float*  bcf    = (float*) alloc(128*4);
    ushort* wb1    = (ushort*)alloc(16384*2);   // frag-major bf16 W1
    ushort* wb2    = (ushort*)alloc(16384*2);   // frag-major bf16 W2
    int*    srcb   = (int*)   alloc((size_t)E*4);
    ushort* Hp     = (ushort*)alloc((size_t)M*DD*2);
    ushort* X2     = (ushort*)alloc((size_t)M*DD*2);
    uint2*  pairs  = (uint2*)Hp;   // alias: pairs (E*8B) used only before k_gemm writes Hp
    (void)ws_size; (void)n_in;

    k_detect<<<1, 64, 0, stream>>>(ei, (const ushort*)x, (const ushort*)W1, flags);
    k_canon <<<194, 256, 0, stream>>>(W1, W2, Wfc, b1, b2, bfc,
                                      Wc1, Wc2, Wcf, bc1, bc2, bcf, wb1, wb2, flags);
    k_init  <<<(G*DD+255)/256, 256, 0, stream>>>(pooled, G*DD, buktot, nbuk);

    // counting-sort CSR build (hierarchical scan)
    k_hist  <<<NBLK, 256, 0, stream>>>(ei, flags, ghist, buktot, E, nbuk, chunk);
    k_scanB2<<<1, 256, 0, stream>>>(buktot, bukoff, nbuk);
    k_apply <<<nbuk, 256, 0, stream>>>(ghist, bukoff, gstart, nbuk);
    k_scat  <<<NBLK, 256, 0, stream>>>(ei, flags, gstart, pairs, E, nbuk, chunk);
    k_build <<<nbuk, 256, 0, stream>>>(pairs, gstart, rowptr, dinv, srcb, E, nbuk, M);

    // layer 1 (X dtype per flags[1])
    k_gemm  <<<(M+63)/64, 256, 0, stream>>>((const ushort*)x, (const float*)x,
                                            wb1, dinv, flags, 0, Hp, M);
    k_gather<<<(M+3)/4, 256, 0, stream>>>(Hp, rowptr, srcb, dinv, bc1, X2, M);
    // layer 2 (X2 is always bf16)
    k_gemm  <<<(M+63)/64, 256, 0, stream>>>(X2, (const float*)X2,
                                            wb2, dinv, flags, 1, Hp, M);
    k_gather<<<(M+3)/4, 256, 0, stream>>>(Hp, rowptr, srcb, dinv, bc2, X2, M);

    // pool + fc
    k_pool<<<(M+255)/256, 256, 0, stream>>>(X2, bat, flags, pooled, M);
    k_cnt <<<(G+63)/64, 64, 0, stream>>>(bat, flags, cntf, M, G);
    k_fc  <<<G, 128, 0, stream>>>(pooled, cntf, Wcf, bcf, flags, (ushort*)d_out, (float*)d_out);
}

// Round 8
// 348.568 us; speedup vs baseline: 2.0340x; 1.0171x over previous
//
#include <hip/hip_runtime.h>
#include <hip/hip_bf16.h>
#include <stdint.h>

typedef unsigned int uint;
typedef unsigned short ushort;
typedef __attribute__((ext_vector_type(8))) short short8;
typedef __attribute__((ext_vector_type(4))) float floatx4;

#define DD 128
#define BSHIFT 9          // bucket = 512 consecutive dst nodes
#define NBLK 256          // partition blocks for hist/scat

__device__ __forceinline__ float bf2f(ushort h){ return __uint_as_float(((uint)h)<<16); }
__device__ __forceinline__ ushort f2bf(float f){
    uint u = __float_as_uint(f);
    u += 0x7fffu + ((u>>16)&1u);
    return (ushort)(u>>16);
}

// flags[0]=edge_index is int64, flags[1]=x is bf16, flags[2]=W is bf16
__global__ void k_detect(const int* ei, const ushort* x, const ushort* W1, int* flags){
    int t = threadIdx.x;  // 0..63
    unsigned long long b0 = __ballot((t < 32) ? (ei[2*t+1] == 0) : 1);
    uint ex = (((uint)x[2*t])  >> 7) & 0xffu;
    uint ew = (((uint)W1[2*t]) >> 7) & 0xffu;
    unsigned long long b1 = __ballot(ex >= 90u && ex <= 160u);
    unsigned long long b2 = __ballot(ew >= 90u && ew <= 160u);
    if (t == 0){
        flags[0] = (b0 == ~0ull) ? 1 : 0;
        flags[1] = (__popcll(b1) >= 48) ? 1 : 0;
        flags[2] = (__popcll(b2) >= 48) ? 1 : 0;
    }
}

// canonicalize W1,W2,Wfc (+biases) to f32; additionally W1,W2 -> frag-major bf16
__global__ void k_canon(const void* s0,const void* s1,const void* s2,
                        const void* s3,const void* s4,const void* s5,
                        float* d0,float* d1,float* d2,float* d3,float* d4,float* d5,
                        ushort* wb1, ushort* wb2,
                        const int* flags){
    int f = flags[2];
    int i = blockIdx.x*blockDim.x + threadIdx.x;
    const void* s; float* d; int off; int r;
    if (i < 49152){
        r = i>>14; off = i & 16383;
        s = (r==0)?s0:((r==1)?s1:s2);
        d = (r==0)?d0:((r==1)?d1:d2);
    } else {
        int j = i - 49152; r = j>>7; off = j & 127;
        if (r >= 3) return;
        s = (r==0)?s3:((r==1)?s4:s5);
        d = (r==0)?d3:((r==1)?d4:d5);
        d[off] = f ? bf2f(((const ushort*)s)[off]) : ((const float*)s)[off];
        return;
    }
    float val = f ? bf2f(((const ushort*)s)[off]) : ((const float*)s)[off];
    d[off] = val;
    if (r < 2){
        int k = off>>7, n = off&127;
        int c = n>>4, nn = n&15, kk = k>>5, q = (k>>3)&3, j = k&7;
        ushort* wb = (r==0) ? wb1 : wb2;
        wb[((c*4+kk)*64 + q*16 + nn)*8 + j] = f2bf(val);
    }
}

__global__ void k_init(float* pooled, int PM, int* buktot, int nbuk){
    int i = blockIdx.x*blockDim.x + threadIdx.x;
    if (i < PM) pooled[i] = 0.f;
    if (i < nbuk) buktot[i] = 0;
}

// ---- counting-sort CSR build --------------------------------------------
__global__ __launch_bounds__(256) void k_hist(const int* __restrict__ ei,
                                              const int* __restrict__ flags,
                                              int* __restrict__ ghist,
                                              int* __restrict__ buktot,
                                              int E, int nbuk, int chunk){
    __shared__ int lh[1024];
    int f = flags[0];
    int t = threadIdx.x, b = blockIdx.x;
    for (int i=t;i<nbuk;i+=256) lh[i]=0;
    __syncthreads();
    int e0 = b*chunk, e1 = min(E, e0+chunk);
    for (int e=e0+t; e<e1; e+=256){
        int d = f ? ei[2*(E+e)] : ei[E+e];
        atomicAdd(&lh[d>>BSHIFT],1);
    }
    __syncthreads();
    for (int i=t;i<nbuk;i+=256){
        int v = lh[i];
        ghist[i*NBLK + b] = v;
        if (v) atomicAdd(&buktot[i], v);
    }
}

__global__ void k_scanB2(const int* __restrict__ buktot, int* __restrict__ bukoff, int nbuk){
    __shared__ int ts[256];
    int t = threadIdx.x;
    int v = (t<nbuk) ? buktot[t] : 0;
    ts[t] = v; __syncthreads();
    for (int off=1; off<256; off<<=1){
        int x = (t>=off) ? ts[t-off] : 0;
        __syncthreads(); ts[t] += x; __syncthreads();
    }
    if (t<nbuk) bukoff[t] = ts[t] - v;   // exclusive
}

__global__ __launch_bounds__(256) void k_apply(const int* __restrict__ ghist,
                                               const int* __restrict__ bukoff,
                                               int* __restrict__ gstart, int nbuk){
    __shared__ int ts[256];
    int b = blockIdx.x, t = threadIdx.x;
    int v = ghist[b*NBLK + t];
    ts[t] = v; __syncthreads();
    for (int off=1; off<256; off<<=1){
        int x = (t>=off) ? ts[t-off] : 0;
        __syncthreads(); ts[t] += x; __syncthreads();
    }
    gstart[b*NBLK + t] = bukoff[b] + ts[t] - v;
}

__global__ __launch_bounds__(256) void k_scat(const int* __restrict__ ei,
                                              const int* __restrict__ flags,
                                              const int* __restrict__ gstart,
                                              uint2* __restrict__ pairs,
                                              int E, int nbuk, int chunk){
    __shared__ int cur[1024];
    int f = flags[0];
    int t = threadIdx.x, b = blockIdx.x;
    for (int i=t;i<nbuk;i+=256) cur[i] = gstart[i*NBLK + b];
    __syncthreads();
    int e0 = b*chunk, e1 = min(E, e0+chunk);
    for (int e=e0+t; e<e1; e+=256){
        int d = f ? ei[2*(E+e)] : ei[E+e];
        int s = f ? ei[2*e]     : ei[e];
        int p = atomicAdd(&cur[d>>BSHIFT],1);
        pairs[p] = make_uint2((uint)s,(uint)d);
    }
}

__global__ __launch_bounds__(256) void k_build(const uint2* __restrict__ pairs,
                                               const int* __restrict__ gstart,
                                               int* __restrict__ rowptr,
                                               float* __restrict__ dinv,
                                               int* __restrict__ srcb,
                                               int E, int nbuk, int M){
    __shared__ int cnt[512], off[512], cur[512], ps[256];
    int b = blockIdx.x, t = threadIdx.x;
    int base = gstart[b*NBLK];
    int end  = (b+1<nbuk) ? gstart[(b+1)*NBLK] : E;
    for (int i=t;i<512;i+=256) cnt[i]=0;
    __syncthreads();
    for (int e=base+t; e<end; e+=256){
        uint2 pr = pairs[e];
        atomicAdd(&cnt[pr.y & 511],1);
    }
    __syncthreads();
    int c0 = cnt[2*t], c1 = cnt[2*t+1];
    int s = c0+c1;
    ps[t]=s; __syncthreads();
    for (int o2=1;o2<256;o2<<=1){
        int x=(t>=o2)?ps[t-o2]:0; __syncthreads(); ps[t]+=x; __syncthreads();
    }
    int ex = ps[t]-s;
    off[2*t]=ex;    off[2*t+1]=ex+c0;
    cur[2*t]=ex;    cur[2*t+1]=ex+c0;
    __syncthreads();
    for (int i=t;i<512;i+=256){
        int n = (b<<BSHIFT)+i;
        if (n<M){
            rowptr[n] = base + off[i];
            dinv[n]   = rsqrtf((float)(cnt[i]+1));
        }
    }
    if (b==0 && t==0) rowptr[M] = E;
    for (int e=base+t; e<end; e+=256){
        uint2 pr = pairs[e];
        int i = pr.y & 511;
        int p = atomicAdd(&cur[i],1);
        srcb[base+p] = (int)pr.x;
    }
}
// -------------------------------------------------------------------------

// MFMA GEMM: Hp[n,c] = bf16( dinv[n] * sum_k X[n,k]*W[k,c] )
__global__ __launch_bounds__(256) void k_gemm(const ushort* __restrict__ Xb,
                                              const float* __restrict__ Xf,
                                              const ushort* __restrict__ Wb,  // frag-major bf16
                                              const float* __restrict__ dinv,
                                              const int* __restrict__ flags, int force_bf16,
                                              ushort* __restrict__ Hp, int M){
    __shared__ uint4 Xs4[1024];   // [w][kk][lane] 16 KB
    __shared__ uint4 Ws4[2048];   // [c][kk][lane] 32 KB
    int t = threadIdx.x;
    int n0 = blockIdx.x*64;
    int xbf = force_bf16 ? 1 : flags[1];

    {
        const uint4* sW = (const uint4*)Wb;
        #pragma unroll
        for (int j=0;j<8;j++) Ws4[t + j*256] = sW[t + j*256];
    }
    #pragma unroll
    for (int g=0; g<4; g++){
        int u = g*256 + t;
        int row = u>>4, kk = (u>>2)&3, q = u&3;
        int n = n0 + row;
        uint4 o;
        if (n < M){
            if (xbf){
                o = *(const uint4*)(Xb + (size_t)n*DD + kk*32 + q*8);
            } else {
                const float* p = Xf + (size_t)n*DD + kk*32 + q*8;
                float4 a = *(const float4*)p;
                float4 b = *(const float4*)(p+4);
                o.x = (uint)f2bf(a.x) | ((uint)f2bf(a.y)<<16);
                o.y = (uint)f2bf(a.z) | ((uint)f2bf(a.w)<<16);
                o.z = (uint)f2bf(b.x) | ((uint)f2bf(b.y)<<16);
                o.w = (uint)f2bf(b.z) | ((uint)f2bf(b.w)<<16);
            }
        } else { o = make_uint4(0,0,0,0); }
        int w = row>>4, m16 = row&15;
        Xs4[(w*4+kk)*64 + q*16 + m16] = o;
    }
    __syncthreads();

    int wv = t>>6, lane = t&63;
    const ushort* Xs = (const ushort*)Xs4;
    const ushort* Ws = (const ushort*)Ws4;

    floatx4 acc[8];
    #pragma unroll
    for (int c=0;c<8;c++) acc[c] = (floatx4){0.f,0.f,0.f,0.f};

    #pragma unroll
    for (int kk=0;kk<4;kk++){
        short8 af = *(const short8*)(Xs + ((size_t)((wv*4+kk)*64 + lane))*8);
        #pragma unroll
        for (int c=0;c<8;c++){
            short8 bf = *(const short8*)(Ws + ((size_t)((c*4+kk)*64 + lane))*8);
            acc[c] = __builtin_amdgcn_mfma_f32_16x16x32_bf16(af, bf, acc[c], 0, 0, 0);
        }
    }

    int quad = lane>>4, col = lane&15;
    int rbase = n0 + wv*16 + quad*4;
    float dv[4];
    #pragma unroll
    for (int r=0;r<4;r++) dv[r] = (rbase + r < M) ? dinv[rbase + r] : 0.f;
    #pragma unroll
    for (int c=0;c<8;c++){
        #pragma unroll
        for (int r=0;r<4;r++){
            int gn = rbase + r;
            if (gn < M) Hp[(size_t)gn*DD + c*16 + col] = f2bf(acc[c][r]*dv[r]);
        }
    }
}

// gather v2: 1 wave per dst; lane reads uint4 (16B), 16 lanes cover a 256B row,
// 4 quarter-waves process 4 rows per load instr; 8 rows (2 loads) per iter.
// Self-loop folded in as virtual source 0. Cross-quarter reduce via shfl_xor.
__global__ __launch_bounds__(256) void k_gather(const ushort* __restrict__ Hp,
                                                const int* __restrict__ rowptr,
                                                const int* __restrict__ srcb,
                                                const float* __restrict__ dinv,
                                                const float* __restrict__ bc,
                                                ushort* __restrict__ Xout, int M){
    int wid  = (int)((blockIdx.x*(size_t)blockDim.x + threadIdx.x) >> 6);
    int lane = threadIdx.x & 63;
    if (wid >= M) return;
    int q   = lane >> 4;     // quarter 0..3
    int l16 = lane & 15;     // 16B chunk within row
    const uint4* Hp4 = (const uint4*)Hp;

    float acc[8];
    #pragma unroll
    for (int c=0;c<8;c++) acc[c] = 0.f;

    #define ACCUM(vv) { \
        acc[0] += __uint_as_float((vv).x<<16); acc[1] += __uint_as_float((vv).x&0xffff0000u); \
        acc[2] += __uint_as_float((vv).y<<16); acc[3] += __uint_as_float((vv).y&0xffff0000u); \
        acc[4] += __uint_as_float((vv).z<<16); acc[5] += __uint_as_float((vv).z&0xffff0000u); \
        acc[6] += __uint_as_float((vv).w<<16); acc[7] += __uint_as_float((vv).w&0xffff0000u); }

    int rp  = rowptr[wid];
    int rp1 = rowptr[wid+1];
    int total = (rp1 - rp) + 1;          // + self-loop at position 0
    int j = 0;
    while (j < total){
        int m = total - j; if (m > 64) m = 64;
        int pos = j + lane;
        int idx = wid;
        if (lane < m && pos > 0) idx = srcb[rp + pos - 1];
        for (int g = 0; g < m; g += 8){
            int r0 = g + q, r1 = g + 4 + q;
            int s0 = __shfl(idx, r0, 64);
            int s1 = __shfl(idx, r1, 64);
            uint4 v0 = make_uint4(0,0,0,0), v1 = make_uint4(0,0,0,0);
            if (r0 < m) v0 = Hp4[(size_t)s0*16 + l16];
            if (r1 < m) v1 = Hp4[(size_t)s1*16 + l16];
            ACCUM(v0);
            ACCUM(v1);
        }
        j += m;
    }
    #undef ACCUM

    // reduce across quarters: lanes l, l+16, l+32, l+48 hold partial sums of same channels
    #pragma unroll
    for (int c=0;c<8;c++){
        acc[c] += __shfl_xor(acc[c], 16, 64);
        acc[c] += __shfl_xor(acc[c], 32, 64);
    }

    if (lane < 16){
        float w = dinv[wid];
        const float* bp = bc + l16*8;
        uint4 o;
        float r0,r1;
        r0 = fmaxf(fmaf(acc[0], w, bp[0]), 0.f);
        r1 = fmaxf(fmaf(acc[1], w, bp[1]), 0.f);
        o.x = (uint)f2bf(r0) | ((uint)f2bf(r1)<<16);
        r0 = fmaxf(fmaf(acc[2], w, bp[2]), 0.f);
        r1 = fmaxf(fmaf(acc[3], w, bp[3]), 0.f);
        o.y = (uint)f2bf(r0) | ((uint)f2bf(r1)<<16);
        r0 = fmaxf(fmaf(acc[4], w, bp[4]), 0.f);
        r1 = fmaxf(fmaf(acc[5], w, bp[5]), 0.f);
        o.z = (uint)f2bf(r0) | ((uint)f2bf(r1)<<16);
        r0 = fmaxf(fmaf(acc[6], w, bp[6]), 0.f);
        r1 = fmaxf(fmaf(acc[7], w, bp[7]), 0.f);
        o.w = (uint)f2bf(r0) | ((uint)f2bf(r1)<<16);
        ((uint4*)Xout)[(size_t)wid*16 + l16] = o;
    }
}

// mean-pool numerator (latency-optimized)
__global__ __launch_bounds__(256) void k_pool(const ushort* __restrict__ X3,
                                              const int* __restrict__ batch,
                                              const int* __restrict__ flags,
                                              float* __restrict__ pooled, int M){
    int f = flags[0];
    int t = threadIdx.x;
    int c32 = t & 63;
    int row = t >> 6;
    int n0 = blockIdx.x * 256;
    if (n0 >= M) return;
    int nend = n0 + 256; if (nend > M) nend = M;
    const uint* X3u = (const uint*)X3;

    float a0 = 0.f, a1 = 0.f;
    int cur = -1;

    int n = n0 + row;
    #define POOL_PROC(gg, uu) \
        if ((gg) != cur){ \
            if (cur >= 0){ \
                atomicAdd(&pooled[cur*DD + 2*c32],   a0); \
                atomicAdd(&pooled[cur*DD + 2*c32+1], a1); \
            } \
            a0 = 0.f; a1 = 0.f; cur = (gg); \
        } \
        a0 += __uint_as_float((uu)<<16); \
        a1 += __uint_as_float((uu) & 0xffff0000u);

    for (; n + 12 < nend; n += 16){
        int g0 = f ? batch[2*n]      : batch[n];
        int g1 = f ? batch[2*(n+4)]  : batch[n+4];
        int g2 = f ? batch[2*(n+8)]  : batch[n+8];
        int g3 = f ? batch[2*(n+12)] : batch[n+12];
        uint u0 = X3u[(size_t)n*64      + c32];
        uint u1 = X3u[(size_t)(n+4)*64  + c32];
        uint u2 = X3u[(size_t)(n+8)*64  + c32];
        uint u3 = X3u[(size_t)(n+12)*64 + c32];
        POOL_PROC(g0, u0);
        POOL_PROC(g1, u1);
        POOL_PROC(g2, u2);
        POOL_PROC(g3, u3);
    }
    for (; n < nend; n += 4){
        int g = f ? batch[2*n] : batch[n];
        uint u = X3u[(size_t)n*64 + c32];
        POOL_PROC(g, u);
    }
    #undef POOL_PROC

    if (cur >= 0){
        atomicAdd(&pooled[cur*DD + 2*c32],   a0);
        atomicAdd(&pooled[cur*DD + 2*c32+1], a1);
    }
}

__global__ void k_cnt(const int* __restrict__ batch, const int* __restrict__ flags,
                      float* __restrict__ cntf, int M, int G){
    int f = flags[0];
    int g = blockIdx.x*blockDim.x + threadIdx.x;
    if (g >= G) return;
    int lo = 0, hi = M;
    while (lo < hi){ int mid = (lo+hi)>>1; int bv = f ? batch[2*mid] : batch[mid]; if (bv > g) hi = mid; else lo = mid+1; }
    int ub_g = lo;
    lo = 0; hi = M;
    while (lo < hi){ int mid = (lo+hi)>>1; int bv = f ? batch[2*mid] : batch[mid]; if (bv > g-1) hi = mid; else lo = mid+1; }
    cntf[g] = (float)(ub_g - lo);
}

__global__ void k_fc(const float* __restrict__ pooled, const float* __restrict__ cntf,
                     const float* __restrict__ Wcf, const float* __restrict__ bcf,
                     const int* __restrict__ flags, ushort* out16, float* out32){
    __shared__ float p[128];
    int g = blockIdx.x, c = threadIdx.x;
    p[c] = pooled[g*DD + c] / fmaxf(cntf[g], 1.f);
    __syncthreads();
    float acc = bcf[c];
    #pragma unroll 8
    for (int k=0;k<128;k++) acc = fmaf(p[k], Wcf[k*DD + c], acc);
    float r = fmaxf(acc, 0.f);
    if (flags[1]) out16[g*DD + c] = f2bf(r);
    else          out32[g*DD + c] = r;
}

extern "C" void kernel_launch(void* const* d_in, const int* in_sizes, int n_in,
                              void* d_out, int out_size, void* d_ws, size_t ws_size,
                              hipStream_t stream) {
    const void* x    = d_in[0];
    const int*  ei   = (const int*)d_in[1];
    const int*  bat  = (const int*)d_in[2];
    const void* W1   = d_in[3];
    const void* b1   = d_in[4];
    const void* W2   = d_in[5];
    const void* b2   = d_in[6];
    const void* Wfc  = d_in[7];
    const void* bfc  = d_in[8];

    int M = in_sizes[0] / DD;       // 100000 nodes
    int E = in_sizes[1] / 2;        // 1600000 edges
    int G = out_size / DD;          // 64 graphs
    int nbuk  = (M + 511) >> BSHIFT;        // 196 buckets of 512 dsts
    int chunk = (E + NBLK - 1) / NBLK;

    char* w = (char*)d_ws;
    auto alloc = [&](size_t bytes)->void*{ void* p = (void*)w; w += (bytes + 255) & ~(size_t)255; return p; };
    int*    flags  = (int*)   alloc(16);
    int*    rowptr = (int*)   alloc((size_t)(M+1)*4);
    int*    ghist  = (int*)   alloc((size_t)nbuk*NBLK*4);
    int*    gstart = (int*)   alloc((size_t)nbuk*NBLK*4);
    int*    buktot = (int*)   alloc((size_t)nbuk*4);
    int*    bukoff = (int*)   alloc((size_t)nbuk*4);
    float*  dinv   = (float*) alloc((size_t)M*4);
    float*  cntf   = (float*) alloc((size_t)G*4);
    float*  pooled = (float*) alloc((size_t)G*DD*4);
    float*  Wc1    = (float*) alloc(16384*4);
    float*  Wc2    = (float*) alloc(16384*4);
    float*  Wcf    = (float*) alloc(16384*4);
    float*  bc1    = (float*) alloc(128*4);
    float*  bc2    = (float*) alloc(128*4);
    float*  bcf    = (float*) alloc(128*4);
    ushort* wb1    = (ushort*)alloc(16384*2);   // frag-major bf16 W1
    ushort* wb2    = (ushort*)alloc(16384*2);   // frag-major bf16 W2
    int*    srcb   = (int*)   alloc((size_t)E*4);
    ushort* Hp     = (ushort*)alloc((size_t)M*DD*2);
    ushort* X2     = (ushort*)alloc((size_t)M*DD*2);
    uint2*  pairs  = (uint2*)Hp;   // alias: pairs (E*8B) used only before k_gemm writes Hp
    (void)ws_size; (void)n_in;

    k_detect<<<1, 64, 0, stream>>>(ei, (const ushort*)x, (const ushort*)W1, flags);
    k_canon <<<194, 256, 0, stream>>>(W1, W2, Wfc, b1, b2, bfc,
                                      Wc1, Wc2, Wcf, bc1, bc2, bcf, wb1, wb2, flags);
    k_init  <<<(G*DD+255)/256, 256, 0, stream>>>(pooled, G*DD, buktot, nbuk);

    // counting-sort CSR build (hierarchical scan)
    k_hist  <<<NBLK, 256, 0, stream>>>(ei, flags, ghist, buktot, E, nbuk, chunk);
    k_scanB2<<<1, 256, 0, stream>>>(buktot, bukoff, nbuk);
    k_apply <<<nbuk, 256, 0, stream>>>(ghist, bukoff, gstart, nbuk);
    k_scat  <<<NBLK, 256, 0, stream>>>(ei, flags, gstart, pairs, E, nbuk, chunk);
    k_build <<<nbuk, 256, 0, stream>>>(pairs, gstart, rowptr, dinv, srcb, E, nbuk, M);

    // layer 1 (X dtype per flags[1])
    k_gemm  <<<(M+63)/64, 256, 0, stream>>>((const ushort*)x, (const float*)x,
                                            wb1, dinv, flags, 0, Hp, M);
    k_gather<<<(M+3)/4, 256, 0, stream>>>(Hp, rowptr, srcb, dinv, bc1, X2, M);
    // layer 2 (X2 is always bf16)
    k_gemm  <<<(M+63)/64, 256, 0, stream>>>(X2, (const float*)X2,
                                            wb2, dinv, flags, 1, Hp, M);
    k_gather<<<(M+3)/4, 256, 0, stream>>>(Hp, rowptr, srcb, dinv, bc2, X2, M);

    // pool + fc
    k_pool<<<(M+255)/256, 256, 0, stream>>>(X2, bat, flags, pooled, M);
    k_cnt <<<(G+63)/64, 64, 0, stream>>>(bat, flags, cntf, M, G);
    k_fc  <<<G, 128, 0, stream>>>(pooled, cntf, Wcf, bcf, flags, (ushort*)d_out, (float*)d_out);
}